// Round 13
// baseline (514.484 us; speedup 1.0000x reference)
//
#include <hip/hip_runtime.h>
#include <hip/hip_bf16.h>

#define B_ 16
#define S_ 4096
#define O_ 512
#define D_ 128
#define NEG_INF_ -1e8f
#define MAX_ITER_ 10
#define YST 513

typedef __attribute__((ext_vector_type(8))) short short8;
typedef __attribute__((ext_vector_type(4))) float floatx4;
typedef __attribute__((ext_vector_type(4))) unsigned short ushort4v;
typedef __attribute__((ext_vector_type(4))) _Float16 half4v;
typedef __attribute__((ext_vector_type(8))) _Float16 half8v;

__device__ inline unsigned short f32_to_bf16_rne(float x) {
    union { float f; unsigned int u; } c; c.f = x;
    unsigned int u = c.u;
    unsigned int r = (u + 0x7FFFu + ((u >> 16) & 1u)) >> 16;
    return (unsigned short)r;
}
__device__ inline float bf16_bits_to_f32(unsigned short h) {
    union { unsigned int u; float f; } c; c.u = ((unsigned int)h) << 16;
    return c.f;
}

// ---------------- init: loga from mask, zero u,v ----------------
__global__ void init_kernel(const int* __restrict__ mask,
                            float* __restrict__ u, float* __restrict__ v,
                            float* __restrict__ loga) {
    __shared__ int sc[256];
    int b = blockIdx.x, t = threadIdx.x;
    int c = 0;
    for (int k = t; k < S_; k += 256) c += (mask[(size_t)b * S_ + k] != 0);
    sc[t] = c; __syncthreads();
    for (int st = 128; st > 0; st >>= 1) { if (t < st) sc[t] += sc[t + st]; __syncthreads(); }
    if (t == 0) loga[b] = logf((float)O_ / (float)sc[0]);
    for (int k = t; k < S_; k += 256) u[(size_t)b * S_ + k] = 0.f;
    for (int k = t; k < O_; k += 256) v[b * O_ + k] = 0.f;
}

// ---------------- pre-split f32 -> bf16 hi/lo (both arrays, one launch) ----------------
__global__ __launch_bounds__(256) void split_kernel(const float* __restrict__ srcA,
                                                    unsigned short* __restrict__ hiA,
                                                    unsigned short* __restrict__ loA, int n4A,
                                                    const float* __restrict__ srcB,
                                                    unsigned short* __restrict__ hiB,
                                                    unsigned short* __restrict__ loB, int n4B) {
    int i = blockIdx.x * 256 + threadIdx.x;
    const float* src; unsigned short* hi; unsigned short* lo;
    if (i < n4A) { src = srcA; hi = hiA; lo = loA; }
    else if (i < n4A + n4B) { i -= n4A; src = srcB; hi = hiB; lo = loB; }
    else return;
    float4 x = ((const float4*)src)[i];
    float xs[4] = {x.x, x.y, x.z, x.w};
    ushort4v h, l;
#pragma unroll
    for (int j = 0; j < 4; ++j) {
        unsigned short hh = f32_to_bf16_rne(xs[j]);
        float rem = xs[j] - bf16_bits_to_f32(hh);
        h[j] = hh; l[j] = f32_to_bf16_rne(rem);
    }
    ((ushort4v*)hi)[i] = h;
    ((ushort4v*)lo)[i] = l;
}

// ================= gemm: 256s x 64o per block, iou REGISTER-PREFETCHED =================
// A=target (o rows), B=input (s cols): C row=o (kg*4+r contiguous), col=s.
// The 16 iou float4 loads are issued BEFORE the MFMA loop so their HBM latency
// hides under ~48 MFMAs (r8 epilogue-load variant exposed it serially).
__global__ __launch_bounds__(256) void gemm_nat(const unsigned short* __restrict__ in_hi,
                                                const unsigned short* __restrict__ in_lo,
                                                const unsigned short* __restrict__ tg_hi,
                                                const unsigned short* __restrict__ tg_lo,
                                                const float* __restrict__ iou,
                                                float* __restrict__ K) {
    int b = blockIdx.z;
    int s0 = blockIdx.x * 256;
    int o0 = blockIdx.y * 64;
    int t = threadIdx.x, wid = t >> 6, lane = t & 63, fr = lane & 15, kg = lane >> 4;

    // early-issue iou prefetch
    float4 ivp[4][4];
#pragma unroll
    for (int i = 0; i < 4; ++i) {
        int s = s0 + wid * 64 + i * 16 + fr;
        size_t rowb = ((size_t)b * S_ + s) * O_;
#pragma unroll
        for (int j = 0; j < 4; ++j)
            ivp[i][j] = *(const float4*)(iou + rowb + o0 + j * 16 + kg * 4);
    }

    const unsigned short* ih = in_hi + ((size_t)b * S_ + s0 + wid * 64 + fr) * D_;
    const unsigned short* il = in_lo + ((size_t)b * S_ + s0 + wid * 64 + fr) * D_;
    const unsigned short* th = tg_hi + ((size_t)b * O_ + o0 + fr) * D_;
    const unsigned short* tl = tg_lo + ((size_t)b * O_ + o0 + fr) * D_;

    floatx4 acc[4][4];
#pragma unroll
    for (int i = 0; i < 4; ++i)
#pragma unroll
        for (int j = 0; j < 4; ++j) acc[i][j] = (floatx4){0.f, 0.f, 0.f, 0.f};

#pragma unroll
    for (int kb = 0; kb < 4; ++kb) {
        int ko = kb * 32 + kg * 8;
        short8 T_h[4], T_l[4];
#pragma unroll
        for (int j = 0; j < 4; ++j) {
            T_h[j] = *(const short8*)(th + (size_t)j * 16 * D_ + ko);
            T_l[j] = *(const short8*)(tl + (size_t)j * 16 * D_ + ko);
        }
#pragma unroll
        for (int i = 0; i < 4; ++i) {
            short8 I_h = *(const short8*)(ih + (size_t)i * 16 * D_ + ko);
            short8 I_l = *(const short8*)(il + (size_t)i * 16 * D_ + ko);
#pragma unroll
            for (int j = 0; j < 4; ++j) {
                acc[i][j] = __builtin_amdgcn_mfma_f32_16x16x32_bf16(T_l[j], I_h, acc[i][j], 0, 0, 0);
                acc[i][j] = __builtin_amdgcn_mfma_f32_16x16x32_bf16(T_h[j], I_l, acc[i][j], 0, 0, 0);
                acc[i][j] = __builtin_amdgcn_mfma_f32_16x16x32_bf16(T_h[j], I_h, acc[i][j], 0, 0, 0);
            }
        }
    }

#pragma unroll
    for (int i = 0; i < 4; ++i) {
        int s = s0 + wid * 64 + i * 16 + fr;
        float sn = (float)s * (1.0f / S_);
        size_t rowb = ((size_t)b * S_ + s) * O_;
#pragma unroll
        for (int j = 0; j < 4; ++j) {
            int ob = o0 + j * 16 + kg * 4;
            float4 iv = ivp[i][j];
            float ivs[4] = {iv.x, iv.y, iv.z, iv.w};
            float tmp[4];
#pragma unroll
            for (int r = 0; r < 4; ++r) {
                float d = sn - (float)(ob + r) * (1.0f / O_);
                float pf = __expf(-100.0f * d * d);
                tmp[r] = pf * (acc[i][j][r] - ivs[r]) * 10.0f;
            }
            float4 q; q.x = tmp[0]; q.y = tmp[1]; q.z = tmp[2]; q.w = tmp[3];
            *(float4*)(K + rowb + ob) = q;
        }
    }
}

// ================= TIER A: fp16 shadow z = K + u1 =================

// iteration 1: reads f32 K, writes u1 (to u and u1c), colma, and zh = fp16(K+u1).
__global__ __launch_bounds__(256) void sink_first_z(const float* __restrict__ K,
                                                    float* __restrict__ u,
                                                    float* __restrict__ u1c,
                                                    _Float16* __restrict__ zh,
                                                    float2* __restrict__ colma,
                                                    const int* __restrict__ mask,
                                                    const float* __restrict__ loga) {
    __shared__ float sy[16 * YST];
    int b = blockIdx.y;
    int t = threadIdx.x, fr = t & 15, sl = t >> 4;
    int sbase = blockIdx.x * 64;
    float lg = loga[b];
    float Mc0 = -INFINITY, Ac0 = 0.f, Mc1 = -INFINITY, Ac1 = 0.f;

    float bufA[32], bufB[32];
    auto loadK = [&](float (&dst)[32], int tau) {
        const float* krow = K + ((size_t)b * S_ + sbase + tau * 16 + sl) * O_ + fr * 4;
#pragma unroll
        for (int k = 0; k < 8; ++k) {
            float4 q = *(const float4*)(krow + k * 64);
            dst[k * 4 + 0] = q.x; dst[k * 4 + 1] = q.y;
            dst[k * 4 + 2] = q.z; dst[k * 4 + 3] = q.w;
        }
    };
    auto process = [&](float (&cur)[32], float (&nxt)[32], int tau, bool pre) {
        int s = sbase + tau * 16 + sl;
        size_t srow = (size_t)b * S_ + s;
        int mk = mask[srow];
        if (pre) loadK(nxt, tau + 1);

        // phase A: row LSE over 16 lanes (uold=0, v=0 -> x = K)
        float M = -INFINITY;
#pragma unroll
        for (int i = 0; i < 32; ++i) M = fmaxf(M, cur[i]);
#pragma unroll
        for (int off = 1; off < 16; off <<= 1) M = fmaxf(M, __shfl_xor(M, off));
        float a = 0.f;
#pragma unroll
        for (int i = 0; i < 32; ++i) a += __expf(cur[i] - M);
#pragma unroll
        for (int off = 1; off < 16; off <<= 1) a += __shfl_xor(a, off);
        float unew = lg - (M + logf(a));
        if (!mk) unew = NEG_INF_;
        if (fr == 0) { u[srow] = unew; u1c[srow] = unew; }

        float c = unew;   // y = K + u1
        _Float16* zw = zh + srow * O_ + fr * 4;
#pragma unroll
        for (int k = 0; k < 8; ++k) {
            float y0 = cur[k * 4 + 0] + c, y1 = cur[k * 4 + 1] + c;
            float y2 = cur[k * 4 + 2] + c, y3 = cur[k * 4 + 3] + c;
            float4 q; q.x = y0; q.y = y1; q.z = y2; q.w = y3;
            *(float4*)&sy[sl * YST + fr * 4 + k * 64] = q;
            half4v hq;
            hq[0] = (_Float16)y0; hq[1] = (_Float16)y1;
            hq[2] = (_Float16)y2; hq[3] = (_Float16)y3;
            *(half4v*)(zw + k * 64) = hq;
        }
        __syncthreads();
#pragma unroll
        for (int h = 0; h < 2; ++h) {
            int o = t + h * 256;
            float q[16];
            float m = -INFINITY;
#pragma unroll
            for (int r = 0; r < 16; ++r) { q[r] = sy[r * YST + o]; m = fmaxf(m, q[r]); }
            float aa = 0.f;
#pragma unroll
            for (int r = 0; r < 16; ++r) aa += __expf(q[r] - m);
            float Mo = h ? Mc1 : Mc0, Ao = h ? Ac1 : Ac0;
            float nm = fmaxf(Mo, m);
            Ao = Ao * __expf(Mo - nm) + aa * __expf(m - nm);
            if (h) { Mc1 = nm; Ac1 = Ao; } else { Mc0 = nm; Ac0 = Ao; }
        }
        __syncthreads();
    };
    loadK(bufA, 0);
    process(bufA, bufB, 0, true);
    process(bufB, bufA, 1, true);
    process(bufA, bufB, 2, true);
    process(bufB, bufA, 3, false);

    float2* cout = colma + ((size_t)b * 64 + blockIdx.x) * O_;
    {
        float2 r0; r0.x = Mc0; r0.y = Ac0; cout[t] = r0;
        float2 r1; r1.x = Mc1; r1.y = Ac1; cout[t + 256] = r1;
    }
}

// iterations 2..10: read fp16 z via 16B half8 loads; x = z + (uold-u1) + v.
// Lane column mapping o = fr*8 + j + k*128 (row LSE is permutation-invariant).
__global__ __launch_bounds__(256) void sink_late(const _Float16* __restrict__ zh,
                                                 const float* __restrict__ vin,
                                                 float* __restrict__ u,
                                                 const float* __restrict__ u1c,
                                                 float2* __restrict__ colma,
                                                 const int* __restrict__ mask,
                                                 const float* __restrict__ loga) {
    __shared__ float sv[O_];
    __shared__ float sy[16 * YST];
    int b = blockIdx.y;
    int t = threadIdx.x, fr = t & 15, sl = t >> 4;
    for (int i = t; i < O_; i += 256) sv[i] = vin[b * O_ + i];
    __syncthreads();
    int sbase = blockIdx.x * 64;
    float lg = loga[b];
    float Mc0 = -INFINITY, Ac0 = 0.f, Mc1 = -INFINITY, Ac1 = 0.f;

    float bufA[32], bufB[32];
    auto loadZ = [&](float (&dst)[32], int tau) {
        const _Float16* zrow = zh + ((size_t)b * S_ + sbase + tau * 16 + sl) * O_ + fr * 8;
#pragma unroll
        for (int k = 0; k < 4; ++k) {
            half8v q = *(const half8v*)(zrow + k * 128);
#pragma unroll
            for (int j = 0; j < 8; ++j)
                dst[k * 8 + j] = fmaxf((float)q[j], NEG_INF_);
        }
    };
    auto process = [&](float (&cur)[32], float (&nxt)[32], int tau, bool pre) {
        int s = sbase + tau * 16 + sl;
        size_t srow = (size_t)b * S_ + s;
        float uold = u[srow];
        float du = uold - u1c[srow];
        int mk = mask[srow];
        if (pre) loadZ(nxt, tau + 1);

        float xv[32];
#pragma unroll
        for (int k = 0; k < 4; ++k) {
            float4 v0 = *(const float4*)&sv[fr * 8 + k * 128];
            float4 v1 = *(const float4*)&sv[fr * 8 + k * 128 + 4];
            xv[k * 8 + 0] = cur[k * 8 + 0] + du + v0.x;
            xv[k * 8 + 1] = cur[k * 8 + 1] + du + v0.y;
            xv[k * 8 + 2] = cur[k * 8 + 2] + du + v0.z;
            xv[k * 8 + 3] = cur[k * 8 + 3] + du + v0.w;
            xv[k * 8 + 4] = cur[k * 8 + 4] + du + v1.x;
            xv[k * 8 + 5] = cur[k * 8 + 5] + du + v1.y;
            xv[k * 8 + 6] = cur[k * 8 + 6] + du + v1.z;
            xv[k * 8 + 7] = cur[k * 8 + 7] + du + v1.w;
        }
        // phase A: row LSE (max-guarded)
        float M = -INFINITY;
#pragma unroll
        for (int i = 0; i < 32; ++i) M = fmaxf(M, xv[i]);
#pragma unroll
        for (int off = 1; off < 16; off <<= 1) M = fmaxf(M, __shfl_xor(M, off));
        float a = 0.f;
#pragma unroll
        for (int i = 0; i < 32; ++i) a += __expf(xv[i] - M);
#pragma unroll
        for (int off = 1; off < 16; off <<= 1) a += __shfl_xor(a, off);
        float unew = lg - (M + logf(a));
        if (!mk) unew = NEG_INF_;
        if (fr == 0) u[srow] = unew;

        float c = unew - uold;
#pragma unroll
        for (int k = 0; k < 4; ++k) {
            float4 q0, q1;
            q0.x = xv[k * 8 + 0] + c; q0.y = xv[k * 8 + 1] + c;
            q0.z = xv[k * 8 + 2] + c; q0.w = xv[k * 8 + 3] + c;
            q1.x = xv[k * 8 + 4] + c; q1.y = xv[k * 8 + 5] + c;
            q1.z = xv[k * 8 + 6] + c; q1.w = xv[k * 8 + 7] + c;
            *(float4*)&sy[sl * YST + fr * 8 + k * 128] = q0;
            *(float4*)&sy[sl * YST + fr * 8 + k * 128 + 4] = q1;
        }
        __syncthreads();
#pragma unroll
        for (int h = 0; h < 2; ++h) {
            int o = t + h * 256;
            float q[16];
            float m = -INFINITY;
#pragma unroll
            for (int r = 0; r < 16; ++r) { q[r] = sy[r * YST + o]; m = fmaxf(m, q[r]); }
            float aa = 0.f;
#pragma unroll
            for (int r = 0; r < 16; ++r) aa += __expf(q[r] - m);
            float Mo = h ? Mc1 : Mc0, Ao = h ? Ac1 : Ac0;
            float nm = fmaxf(Mo, m);
            Ao = Ao * __expf(Mo - nm) + aa * __expf(m - nm);
            if (h) { Mc1 = nm; Ac1 = Ao; } else { Mc0 = nm; Ac0 = Ao; }
        }
        __syncthreads();
    };
    loadZ(bufA, 0);
    process(bufA, bufB, 0, true);
    process(bufB, bufA, 1, true);
    process(bufA, bufB, 2, true);
    process(bufB, bufA, 3, false);

    float2* cout = colma + ((size_t)b * 64 + blockIdx.x) * O_;
    {
        float2 r0; r0.x = Mc0; r0.y = Ac0; cout[t] = r0;
        float2 r1; r1.x = Mc1; r1.y = Ac1; cout[t + 256] = r1;
    }
}

// final (tier A): out = 4096*exp(z + (u10-u1) + v10 - 100 d^2), LDS transpose
__global__ __launch_bounds__(256) void final_tr_z(const _Float16* __restrict__ zh,
                                                  const float* __restrict__ u,
                                                  const float* __restrict__ u1c,
                                                  const float* __restrict__ v,
                                                  float* __restrict__ out) {
    __shared__ float tile[64][65];
    __shared__ float sdu[64], svv[64];
    int b = blockIdx.z;
    int s0 = blockIdx.x * 64, o0 = blockIdx.y * 64;
    int t = threadIdx.x, fr = t & 15, rg = t >> 4;
    if (t < 64) sdu[t] = u[(size_t)b * S_ + s0 + t] - u1c[(size_t)b * S_ + s0 + t];
    else if (t < 128) svv[t - 64] = v[b * O_ + o0 + t - 64];
    __syncthreads();
#pragma unroll
    for (int p = 0; p < 4; ++p) {
        int sl = p * 16 + rg;
        int s = s0 + sl;
        half4v hx = *(const half4v*)(zh + ((size_t)b * S_ + s) * O_ + o0 + fr * 4);
        float du = sdu[sl];
        float sn = (float)s * (1.0f / S_);
#pragma unroll
        for (int c = 0; c < 4; ++c) {
            int ol = fr * 4 + c;
            float zf = fmaxf((float)hx[c], NEG_INF_);
            float d = sn - (float)(o0 + ol) * (1.0f / O_);
            tile[ol][sl] = 4096.0f * __expf(zf + du + svv[ol] - 100.0f * d * d);
        }
    }
    __syncthreads();
#pragma unroll
    for (int p = 0; p < 4; ++p) {
        int ol = p * 16 + rg;
        float4 y;
        y.x = tile[ol][fr * 4 + 0];
        y.y = tile[ol][fr * 4 + 1];
        y.z = tile[ol][fr * 4 + 2];
        y.w = tile[ol][fr * 4 + 3];
        *(float4*)(out + ((size_t)b * O_ + o0 + ol) * S_ + s0 + fr * 4) = y;
    }
}

// ================= TIER B (round-11 proven, f32 K all the way) =================

template <int FIRST>
__global__ __launch_bounds__(256) void sink_iter(const float* __restrict__ K,
                                                 const float* __restrict__ vin,
                                                 float* __restrict__ u,
                                                 float2* __restrict__ colma,
                                                 const int* __restrict__ mask,
                                                 const float* __restrict__ loga) {
    __shared__ float sv[O_];
    __shared__ float sy[16 * YST];
    int b = blockIdx.y;
    int t = threadIdx.x, fr = t & 15, sl = t >> 4;
    if (!FIRST) {
        for (int i = t; i < O_; i += 256) sv[i] = vin[b * O_ + i];
        __syncthreads();
    }
    int sbase = blockIdx.x * 64;
    float lg = loga[b];
    float Mc0 = -INFINITY, Ac0 = 0.f, Mc1 = -INFINITY, Ac1 = 0.f;

    float bufA[32], bufB[32];
    auto loadK = [&](float (&dst)[32], int tau) {
        const float* krow = K + ((size_t)b * S_ + sbase + tau * 16 + sl) * O_ + fr * 4;
#pragma unroll
        for (int k = 0; k < 8; ++k) {
            float4 q = *(const float4*)(krow + k * 64);
            dst[k * 4 + 0] = q.x; dst[k * 4 + 1] = q.y;
            dst[k * 4 + 2] = q.z; dst[k * 4 + 3] = q.w;
        }
    };
    auto process = [&](float (&cur)[32], float (&nxt)[32], int tau, bool pre) {
        int s = sbase + tau * 16 + sl;
        size_t srow = (size_t)b * S_ + s;
        float uold = FIRST ? 0.f : u[srow];
        int mk = mask[srow];
        if (pre) loadK(nxt, tau + 1);

        float xv[32];
        if (FIRST) {
#pragma unroll
            for (int i = 0; i < 32; ++i) xv[i] = cur[i];
        } else {
#pragma unroll
            for (int k = 0; k < 8; ++k) {
                float4 vvq = *(const float4*)&sv[fr * 4 + k * 64];
                xv[k * 4 + 0] = cur[k * 4 + 0] + uold + vvq.x;
                xv[k * 4 + 1] = cur[k * 4 + 1] + uold + vvq.y;
                xv[k * 4 + 2] = cur[k * 4 + 2] + uold + vvq.z;
                xv[k * 4 + 3] = cur[k * 4 + 3] + uold + vvq.w;
            }
        }
        float M = -INFINITY;
#pragma unroll
        for (int i = 0; i < 32; ++i) M = fmaxf(M, xv[i]);
#pragma unroll
        for (int off = 1; off < 16; off <<= 1) M = fmaxf(M, __shfl_xor(M, off));
        float a = 0.f;
#pragma unroll
        for (int i = 0; i < 32; ++i) a += __expf(xv[i] - M);
#pragma unroll
        for (int off = 1; off < 16; off <<= 1) a += __shfl_xor(a, off);
        float unew = lg - (M + logf(a));
        if (!mk) unew = NEG_INF_;
        if (fr == 0) u[srow] = unew;

        float c = unew - uold;
#pragma unroll
        for (int k = 0; k < 8; ++k) {
            float4 q;
            q.x = xv[k * 4 + 0] + c; q.y = xv[k * 4 + 1] + c;
            q.z = xv[k * 4 + 2] + c; q.w = xv[k * 4 + 3] + c;
            *(float4*)&sy[sl * YST + fr * 4 + k * 64] = q;
        }
        __syncthreads();
#pragma unroll
        for (int h = 0; h < 2; ++h) {
            int o = t + h * 256;
            float q[16];
            float m = -INFINITY;
#pragma unroll
            for (int r = 0; r < 16; ++r) { q[r] = sy[r * YST + o]; m = fmaxf(m, q[r]); }
            float aa = 0.f;
#pragma unroll
            for (int r = 0; r < 16; ++r) aa += __expf(q[r] - m);
            float Mo = h ? Mc1 : Mc0, Ao = h ? Ac1 : Ac0;
            float nm = fmaxf(Mo, m);
            Ao = Ao * __expf(Mo - nm) + aa * __expf(m - nm);
            if (h) { Mc1 = nm; Ac1 = Ao; } else { Mc0 = nm; Ac0 = Ao; }
        }
        __syncthreads();
    };
    loadK(bufA, 0);
    process(bufA, bufB, 0, true);
    process(bufB, bufA, 1, true);
    process(bufA, bufB, 2, true);
    process(bufB, bufA, 3, false);

    float2* cout = colma + ((size_t)b * 64 + blockIdx.x) * O_;
    {
        float2 r0; r0.x = Mc0; r0.y = Ac0; cout[t] = r0;
        float2 r1; r1.x = Mc1; r1.y = Ac1; cout[t + 256] = r1;
    }
}

// finalize v: merge 64 (m,a) chunks per column (log-space) -> v = -(M + log A)
__global__ __launch_bounds__(256) void finalize_v(const float2* __restrict__ colma,
                                                  float* __restrict__ v) {
    __shared__ float sm[4][64], sa[4][64];
    int b = blockIdx.y;
    int ol = threadIdx.x & 63, cg = threadIdx.x >> 6;
    int o = blockIdx.x * 64 + ol;
    const float2* cp = colma + (size_t)b * 64 * O_ + o;
    float M = -INFINITY, A = 0.f;
#pragma unroll 4
    for (int i = 0; i < 16; ++i) {
        float2 q = cp[(size_t)(cg * 16 + i) * O_];
        float nm = fmaxf(M, q.x);
        A = A * __expf(M - nm) + q.y * __expf(q.x - nm);
        M = nm;
    }
    sm[cg][ol] = M; sa[cg][ol] = A;
    __syncthreads();
    if (threadIdx.x < 64) {
        M = sm[0][ol]; A = sa[0][ol];
#pragma unroll
        for (int i = 1; i < 4; ++i) {
            float mi = sm[i][ol], ai = sa[i][ol];
            float nm = fmaxf(M, mi);
            A = A * __expf(M - nm) + ai * __expf(mi - nm);
            M = nm;
        }
        v[b * O_ + o] = -(M + logf(A));
    }
}

// final (tier B): out = 4096*exp(K + u + v - 100 d^2), LDS transpose
__global__ __launch_bounds__(256) void final_tr(const float* __restrict__ K,
                                                const float* __restrict__ u,
                                                const float* __restrict__ v,
                                                float* __restrict__ out) {
    __shared__ float tile[64][65];
    __shared__ float su[64], svv[64];
    int b = blockIdx.z;
    int s0 = blockIdx.x * 64, o0 = blockIdx.y * 64;
    int t = threadIdx.x, fr = t & 15, rg = t >> 4;
    if (t < 64) su[t] = u[(size_t)b * S_ + s0 + t];
    else if (t < 128) svv[t - 64] = v[b * O_ + o0 + t - 64];
    __syncthreads();
#pragma unroll
    for (int p = 0; p < 4; ++p) {
        int sl = p * 16 + rg;
        int s = s0 + sl;
        float4 x = *(const float4*)(K + ((size_t)b * S_ + s) * O_ + o0 + fr * 4);
        float us = su[sl];
        float sn = (float)s * (1.0f / S_);
        float xs[4] = {x.x, x.y, x.z, x.w};
#pragma unroll
        for (int c = 0; c < 4; ++c) {
            int ol = fr * 4 + c;
            float d = sn - (float)(o0 + ol) * (1.0f / O_);
            tile[ol][sl] = 4096.0f * __expf(xs[c] + us + svv[ol] - 100.0f * d * d);
        }
    }
    __syncthreads();
#pragma unroll
    for (int p = 0; p < 4; ++p) {
        int ol = p * 16 + rg;
        float4 y;
        y.x = tile[ol][fr * 4 + 0];
        y.y = tile[ol][fr * 4 + 1];
        y.z = tile[ol][fr * 4 + 2];
        y.w = tile[ol][fr * 4 + 3];
        *(float4*)(out + ((size_t)b * O_ + o0 + ol) * S_ + s0 + fr * 4) = y;
    }
}

// ================= FALLBACK PATH (round-3 proven, KT in d_out) =================

__global__ __launch_bounds__(256) void gemm_kt2(const unsigned short* __restrict__ in_hi,
                                                const unsigned short* __restrict__ in_lo,
                                                const unsigned short* __restrict__ tg_hi,
                                                const unsigned short* __restrict__ tg_lo,
                                                const float* __restrict__ iou,
                                                float* __restrict__ KT) {
    __shared__ float siou[64 * 65];
    int b = blockIdx.z;
    int s0 = blockIdx.x * 64;
    int o0 = blockIdx.y * 64;
    int t = threadIdx.x;
    {
        const float* ir = iou + ((size_t)b * S_ + s0 + (t >> 2)) * O_ + o0 + (t & 3) * 16;
        float4 q0 = ((const float4*)ir)[0];
        float4 q1 = ((const float4*)ir)[1];
        float4 q2 = ((const float4*)ir)[2];
        float4 q3 = ((const float4*)ir)[3];
        float* dst = &siou[(t >> 2) * 65 + (t & 3) * 16];
        dst[0]=q0.x; dst[1]=q0.y; dst[2]=q0.z; dst[3]=q0.w;
        dst[4]=q1.x; dst[5]=q1.y; dst[6]=q1.z; dst[7]=q1.w;
        dst[8]=q2.x; dst[9]=q2.y; dst[10]=q2.z; dst[11]=q2.w;
        dst[12]=q3.x; dst[13]=q3.y; dst[14]=q3.z; dst[15]=q3.w;
    }
    int w = t >> 6, lane = t & 63, fr = lane & 15, kg = lane >> 4;
    const unsigned short* ta_hi = tg_hi + ((size_t)b * O_ + o0 + w * 16 + fr) * D_;
    const unsigned short* ta_lo = tg_lo + ((size_t)b * O_ + o0 + w * 16 + fr) * D_;
    const unsigned short* ib_hi = in_hi + ((size_t)b * S_ + s0 + fr) * D_;
    const unsigned short* ib_lo = in_lo + ((size_t)b * S_ + s0 + fr) * D_;
    floatx4 acc[4];
#pragma unroll
    for (int st = 0; st < 4; ++st) acc[st] = (floatx4){0.f, 0.f, 0.f, 0.f};
#pragma unroll
    for (int kb = 0; kb < 4; ++kb) {
        int ko = kb * 32 + kg * 8;
        short8 ah = *(const short8*)(ta_hi + ko);
        short8 al2 = *(const short8*)(ta_lo + ko);
#pragma unroll
        for (int st = 0; st < 4; ++st) {
            short8 bh2 = *(const short8*)(ib_hi + (size_t)st * 16 * D_ + ko);
            short8 bl2 = *(const short8*)(ib_lo + (size_t)st * 16 * D_ + ko);
            acc[st] = __builtin_amdgcn_mfma_f32_16x16x32_bf16(al2, bh2, acc[st], 0, 0, 0);
            acc[st] = __builtin_amdgcn_mfma_f32_16x16x32_bf16(ah, bl2, acc[st], 0, 0, 0);
            acc[st] = __builtin_amdgcn_mfma_f32_16x16x32_bf16(ah, bh2, acc[st], 0, 0, 0);
        }
    }
    __syncthreads();
#pragma unroll
    for (int st = 0; st < 4; ++st) {
        int s = s0 + st * 16 + fr;
        float ds = (float)s * (1.0f / S_);
#pragma unroll
        for (int r = 0; r < 4; ++r) {
            int o = o0 + w * 16 + kg * 4 + r;
            float d = ds - (float)o * (1.0f / O_);
            float pf = __expf(-100.0f * d * d);
            float iouv = siou[(st * 16 + fr) * 65 + (w * 16 + kg * 4 + r)];
            KT[((size_t)b * O_ + o) * S_ + s] = pf * (acc[st][r] - iouv) * 10.0f;
        }
    }
}

__global__ __launch_bounds__(256) void row_update2(const float* __restrict__ KT,
                                                   const float* __restrict__ v,
                                                   float* __restrict__ u,
                                                   const int* __restrict__ mask,
                                                   const float* __restrict__ loga) {
    __shared__ float sv[O_];
    __shared__ float lm[4][128], la[4][128];
    int b = blockIdx.y;
    int s0 = blockIdx.x * 128;
    int t = threadIdx.x, lane = t & 63, w = t >> 6;
    for (int i = t; i < O_; i += 256) sv[i] = v[b * O_ + i];
    __syncthreads();
    const float* kt = KT + (size_t)b * O_ * S_ + s0 + lane * 2;
    float m0 = -INFINITY, m1 = -INFINITY, a0 = 0.f, a1 = 0.f;
    int ob = w * 128;
#pragma unroll 8
    for (int i = 0; i < 128; ++i) {
        int o = ob + i;
        float2 x2 = *(const float2*)(kt + (size_t)o * S_);
        float vo = sv[o];
        float x0 = x2.x + vo, x1 = x2.y + vo;
        if (x0 > m0) { a0 = a0 * __expf(m0 - x0) + 1.f; m0 = x0; } else a0 += __expf(x0 - m0);
        if (x1 > m1) { a1 = a1 * __expf(m1 - x1) + 1.f; m1 = x1; } else a1 += __expf(x1 - m1);
    }
    lm[w][lane * 2] = m0;     la[w][lane * 2] = a0;
    lm[w][lane * 2 + 1] = m1; la[w][lane * 2 + 1] = a1;
    __syncthreads();
    if (t < 128) {
        float M = lm[0][t], A = la[0][t];
#pragma unroll
        for (int i = 1; i < 4; ++i) {
            float mi = lm[i][t], ai = la[i][t];
            float nm = fmaxf(M, mi);
            A = A * __expf(M - nm) + ai * __expf(mi - nm);
            M = nm;
        }
        float lse = M + logf(A);
        size_t si = (size_t)b * S_ + s0 + t;
        u[si] = mask[si] ? (loga[b] - u[si] - lse) : NEG_INF_;
    }
}

template <int FIN>
__global__ __launch_bounds__(256) void col_update2(float* __restrict__ KT,
                                                   const float* __restrict__ u,
                                                   float* __restrict__ v) {
    __shared__ float red[8];
    int b = blockIdx.y, o = blockIdx.x;
    int t = threadIdx.x;
    float* kt = KT + ((size_t)b * O_ + o) * S_;
    const float* ub = u + (size_t)b * S_;
    float vold = v[b * O_ + o];
    float xs[16];
    float m = -INFINITY, a = 0.f;
#pragma unroll
    for (int k = 0; k < 4; ++k) {
        int s = k * 1024 + t * 4;
        float4 kx = *(const float4*)(kt + s);
        float4 ux = *(const float4*)(ub + s);
        float x0 = kx.x + ux.x, x1 = kx.y + ux.y, x2 = kx.z + ux.z, x3 = kx.w + ux.w;
        if (FIN) { xs[k*4] = x0; xs[k*4+1] = x1; xs[k*4+2] = x2; xs[k*4+3] = x3; }
        float cm = fmaxf(fmaxf(x0, x1), fmaxf(x2, x3));
        float nm = fmaxf(m, cm);
        a = a * __expf(m - nm) + __expf(x0 - nm) + __expf(x1 - nm)
                               + __expf(x2 - nm) + __expf(x3 - nm);
        m = nm;
    }
#pragma unroll
    for (int off = 1; off < 64; off <<= 1) {
        float mo = __shfl_xor(m, off), ao = __shfl_xor(a, off);
        float nm = fmaxf(m, mo);
        a = a * __expf(m - nm) + ao * __expf(mo - nm);
        m = nm;
    }
    int w = t >> 6;
    if ((t & 63) == 0) { red[w * 2] = m; red[w * 2 + 1] = a; }
    __syncthreads();
    float M = red[0], A = red[1];
#pragma unroll
    for (int i = 1; i < 4; ++i) {
        float mi = red[i * 2], ai = red[i * 2 + 1];
        float nm = fmaxf(M, mi);
        A = A * __expf(M - nm) + ai * __expf(mi - nm);
        M = nm;
    }
    float lse = M + logf(A);
    float vn = -vold - lse;
    if (t == 0) v[b * O_ + o] = vn;
    if (FIN) {
        float oo = (float)o * (1.0f / O_);
#pragma unroll
        for (int k = 0; k < 4; ++k) {
            int s = k * 1024 + t * 4;
            float4 r;
            float rr[4];
#pragma unroll
            for (int j = 0; j < 4; ++j) {
                float d = (float)(s + j) * (1.0f / S_) - oo;
                rr[j] = 4096.0f * __expf(xs[k * 4 + j] + vn - 100.0f * d * d);
            }
            r.x = rr[0]; r.y = rr[1]; r.z = rr[2]; r.w = rr[3];
            *(float4*)(kt + s) = r;
        }
    }
}

// ================= launch =================

extern "C" void kernel_launch(void* const* d_in, const int* in_sizes, int n_in,
                              void* d_out, int out_size, void* d_ws, size_t ws_size,
                              hipStream_t stream) {
    const float* input  = (const float*)d_in[0];
    const float* target = (const float*)d_in[1];
    const float* iou    = (const float*)d_in[2];
    const int*   mask   = (const int*)d_in[3];
    float* out = (float*)d_out;
    float* wsf = (float*)d_ws;

    const size_t N_IN = (size_t)B_ * S_ * D_;   // 8388608
    const size_t N_TG = (size_t)B_ * O_ * D_;   // 1048576
    const size_t NK   = (size_t)B_ * S_ * O_;   // 33554432

    float* u    = wsf;
    float* v    = u + (size_t)B_ * S_;
    float* loga = v + (size_t)B_ * O_;
    float* u1c  = loga + 16;
    float* Knat = u1c + (size_t)B_ * S_;
    char*  region = (char*)(Knat + NK);

    // splits (live only until gemm completes)
    unsigned short* f_in_hi = (unsigned short*)region;
    unsigned short* f_in_lo = f_in_hi + N_IN;
    unsigned short* f_tg_hi = f_in_lo + N_IN;
    unsigned short* f_tg_lo = f_tg_hi + N_TG;
    size_t need_B = (size_t)((char*)(f_tg_lo + N_TG) - (char*)d_ws);

    // tier-A overlay: colma then zh (both live from iter 1 on; splits dead)
    float2* colma = (float2*)region;
    _Float16* zh = (_Float16*)(colma + (size_t)B_ * 64 * O_);
    size_t need_A = (size_t)((char*)(zh + NK) - (char*)d_ws);
    if (need_A < need_B) need_A = need_B;   // splits must also fit

    // fallback layout (round-3)
    unsigned short* m_in_hi = (unsigned short*)(loga + 16);
    unsigned short* m_in_lo = m_in_hi + N_IN;
    unsigned short* m_tg_hi = m_in_lo + N_IN;
    unsigned short* m_tg_lo = m_tg_hi + N_TG;
    size_t need_mid = (size_t)((char*)(m_tg_lo + N_TG) - (char*)d_ws);

    init_kernel<<<B_, 256, 0, stream>>>(mask, u, v, loga);
    int n4A = (int)(N_IN / 4), n4B = (int)(N_TG / 4);

    if (ws_size >= need_A) {
        split_kernel<<<(n4A + n4B + 255) / 256, 256, 0, stream>>>(
            input, f_in_hi, f_in_lo, n4A, target, f_tg_hi, f_tg_lo, n4B);
        gemm_nat<<<dim3(S_ / 256, O_ / 64, B_), 256, 0, stream>>>(f_in_hi, f_in_lo, f_tg_hi, f_tg_lo, iou, Knat);
        sink_first_z<<<dim3(S_ / 64, B_), 256, 0, stream>>>(Knat, u, u1c, zh, colma, mask, loga);
        finalize_v<<<dim3(O_ / 64, B_), 256, 0, stream>>>(colma, v);
        for (int it = 1; it < MAX_ITER_; ++it) {
            sink_late<<<dim3(S_ / 64, B_), 256, 0, stream>>>(zh, v, u, u1c, colma, mask, loga);
            finalize_v<<<dim3(O_ / 64, B_), 256, 0, stream>>>(colma, v);
        }
        final_tr_z<<<dim3(S_ / 64, O_ / 64, B_), 256, 0, stream>>>(zh, u, u1c, v, out);
    } else if (ws_size >= need_B) {
        split_kernel<<<(n4A + n4B + 255) / 256, 256, 0, stream>>>(
            input, f_in_hi, f_in_lo, n4A, target, f_tg_hi, f_tg_lo, n4B);
        gemm_nat<<<dim3(S_ / 256, O_ / 64, B_), 256, 0, stream>>>(f_in_hi, f_in_lo, f_tg_hi, f_tg_lo, iou, Knat);
        for (int it = 0; it < MAX_ITER_; ++it) {
            if (it == 0)
                sink_iter<1><<<dim3(S_ / 64, B_), 256, 0, stream>>>(Knat, v, u, colma, mask, loga);
            else
                sink_iter<0><<<dim3(S_ / 64, B_), 256, 0, stream>>>(Knat, v, u, colma, mask, loga);
            finalize_v<<<dim3(O_ / 64, B_), 256, 0, stream>>>(colma, v);
        }
        final_tr<<<dim3(S_ / 64, O_ / 64, B_), 256, 0, stream>>>(Knat, u, v, out);
    } else if (ws_size >= need_mid) {
        split_kernel<<<(n4A + n4B + 255) / 256, 256, 0, stream>>>(
            input, m_in_hi, m_in_lo, n4A, target, m_tg_hi, m_tg_lo, n4B);
        gemm_kt2<<<dim3(S_ / 64, O_ / 64, B_), 256, 0, stream>>>(m_in_hi, m_in_lo, m_tg_hi, m_tg_lo, iou, out);
        for (int it = 0; it < MAX_ITER_; ++it) {
            row_update2<<<dim3(S_ / 128, B_), 256, 0, stream>>>(out, v, u, mask, loga);
            if (it < MAX_ITER_ - 1)
                col_update2<0><<<dim3(O_, B_), 256, 0, stream>>>(out, u, v);
            else
                col_update2<1><<<dim3(O_, B_), 256, 0, stream>>>(out, u, v);
        }
    }
}

// Round 14
// 487.700 us; speedup vs baseline: 1.0549x; 1.0549x over previous
//
#include <hip/hip_runtime.h>
#include <hip/hip_bf16.h>

#define B_ 16
#define S_ 4096
#define O_ 512
#define D_ 128
#define NEG_INF_ -1e8f
#define MAX_ITER_ 10
#define YST 513

typedef __attribute__((ext_vector_type(8))) short short8;
typedef __attribute__((ext_vector_type(4))) float floatx4;
typedef __attribute__((ext_vector_type(4))) unsigned short ushort4v;
typedef __attribute__((ext_vector_type(4))) _Float16 half4v;

__device__ inline unsigned short f32_to_bf16_rne(float x) {
    union { float f; unsigned int u; } c; c.f = x;
    unsigned int u = c.u;
    unsigned int r = (u + 0x7FFFu + ((u >> 16) & 1u)) >> 16;
    return (unsigned short)r;
}
__device__ inline float bf16_bits_to_f32(unsigned short h) {
    union { unsigned int u; float f; } c; c.u = ((unsigned int)h) << 16;
    return c.f;
}

// ---------------- init: loga from mask, zero u,v ----------------
__global__ void init_kernel(const int* __restrict__ mask,
                            float* __restrict__ u, float* __restrict__ v,
                            float* __restrict__ loga) {
    __shared__ int sc[256];
    int b = blockIdx.x, t = threadIdx.x;
    int c = 0;
    for (int k = t; k < S_; k += 256) c += (mask[(size_t)b * S_ + k] != 0);
    sc[t] = c; __syncthreads();
    for (int st = 128; st > 0; st >>= 1) { if (t < st) sc[t] += sc[t + st]; __syncthreads(); }
    if (t == 0) loga[b] = logf((float)O_ / (float)sc[0]);
    for (int k = t; k < S_; k += 256) u[(size_t)b * S_ + k] = 0.f;
    for (int k = t; k < O_; k += 256) v[b * O_ + k] = 0.f;
}

// ---------------- pre-split f32 -> bf16 hi/lo (both arrays, one launch) ----------------
__global__ __launch_bounds__(256) void split_kernel(const float* __restrict__ srcA,
                                                    unsigned short* __restrict__ hiA,
                                                    unsigned short* __restrict__ loA, int n4A,
                                                    const float* __restrict__ srcB,
                                                    unsigned short* __restrict__ hiB,
                                                    unsigned short* __restrict__ loB, int n4B) {
    int i = blockIdx.x * 256 + threadIdx.x;
    const float* src; unsigned short* hi; unsigned short* lo;
    if (i < n4A) { src = srcA; hi = hiA; lo = loA; }
    else if (i < n4A + n4B) { i -= n4A; src = srcB; hi = hiB; lo = loB; }
    else return;
    float4 x = ((const float4*)src)[i];
    float xs[4] = {x.x, x.y, x.z, x.w};
    ushort4v h, l;
#pragma unroll
    for (int j = 0; j < 4; ++j) {
        unsigned short hh = f32_to_bf16_rne(xs[j]);
        float rem = xs[j] - bf16_bits_to_f32(hh);
        h[j] = hh; l[j] = f32_to_bf16_rne(rem);
    }
    ((ushort4v*)hi)[i] = h;
    ((ushort4v*)lo)[i] = l;
}

// ================= gemm (round-8 proven): 256s x 64o per block =================
__global__ __launch_bounds__(256) void gemm_nat(const unsigned short* __restrict__ in_hi,
                                                const unsigned short* __restrict__ in_lo,
                                                const unsigned short* __restrict__ tg_hi,
                                                const unsigned short* __restrict__ tg_lo,
                                                const float* __restrict__ iou,
                                                float* __restrict__ K) {
    int b = blockIdx.z;
    int s0 = blockIdx.x * 256;
    int o0 = blockIdx.y * 64;
    int t = threadIdx.x, wid = t >> 6, lane = t & 63, fr = lane & 15, kg = lane >> 4;

    const unsigned short* ih = in_hi + ((size_t)b * S_ + s0 + wid * 64 + fr) * D_;
    const unsigned short* il = in_lo + ((size_t)b * S_ + s0 + wid * 64 + fr) * D_;
    const unsigned short* th = tg_hi + ((size_t)b * O_ + o0 + fr) * D_;
    const unsigned short* tl = tg_lo + ((size_t)b * O_ + o0 + fr) * D_;

    floatx4 acc[4][4];
#pragma unroll
    for (int i = 0; i < 4; ++i)
#pragma unroll
        for (int j = 0; j < 4; ++j) acc[i][j] = (floatx4){0.f, 0.f, 0.f, 0.f};

#pragma unroll
    for (int kb = 0; kb < 4; ++kb) {
        int ko = kb * 32 + kg * 8;
        short8 T_h[4], T_l[4];
#pragma unroll
        for (int j = 0; j < 4; ++j) {
            T_h[j] = *(const short8*)(th + (size_t)j * 16 * D_ + ko);
            T_l[j] = *(const short8*)(tl + (size_t)j * 16 * D_ + ko);
        }
#pragma unroll
        for (int i = 0; i < 4; ++i) {
            short8 I_h = *(const short8*)(ih + (size_t)i * 16 * D_ + ko);
            short8 I_l = *(const short8*)(il + (size_t)i * 16 * D_ + ko);
#pragma unroll
            for (int j = 0; j < 4; ++j) {
                acc[i][j] = __builtin_amdgcn_mfma_f32_16x16x32_bf16(T_l[j], I_h, acc[i][j], 0, 0, 0);
                acc[i][j] = __builtin_amdgcn_mfma_f32_16x16x32_bf16(T_h[j], I_l, acc[i][j], 0, 0, 0);
                acc[i][j] = __builtin_amdgcn_mfma_f32_16x16x32_bf16(T_h[j], I_h, acc[i][j], 0, 0, 0);
            }
        }
    }

#pragma unroll
    for (int i = 0; i < 4; ++i) {
        int s = s0 + wid * 64 + i * 16 + fr;
        float sn = (float)s * (1.0f / S_);
        size_t rowb = ((size_t)b * S_ + s) * O_;
#pragma unroll
        for (int j = 0; j < 4; ++j) {
            int ob = o0 + j * 16 + kg * 4;
            float4 iv = *(const float4*)(iou + rowb + ob);
            float ivs[4] = {iv.x, iv.y, iv.z, iv.w};
            float tmp[4];
#pragma unroll
            for (int r = 0; r < 4; ++r) {
                float d = sn - (float)(ob + r) * (1.0f / O_);
                float pf = __expf(-100.0f * d * d);
                tmp[r] = pf * (acc[i][j][r] - ivs[r]) * 10.0f;
            }
            float4 q; q.x = tmp[0]; q.y = tmp[1]; q.z = tmp[2]; q.w = tmp[3];
            *(float4*)(K + rowb + ob) = q;
        }
    }
}

// ================= TIER A: fp16 shadow z = K + u1 =================

// iteration 1: reads f32 K, writes u1 (to u and u1c), colma, and zh = fp16(K+u1).
__global__ __launch_bounds__(256) void sink_first_z(const float* __restrict__ K,
                                                    float* __restrict__ u,
                                                    float* __restrict__ u1c,
                                                    _Float16* __restrict__ zh,
                                                    float2* __restrict__ colma,
                                                    const int* __restrict__ mask,
                                                    const float* __restrict__ loga) {
    __shared__ float sy[16 * YST];
    int b = blockIdx.y;
    int t = threadIdx.x, fr = t & 15, sl = t >> 4;
    int sbase = blockIdx.x * 64;
    float lg = loga[b];
    float Mc0 = -INFINITY, Ac0 = 0.f, Mc1 = -INFINITY, Ac1 = 0.f;

    float bufA[32], bufB[32];
    auto loadK = [&](float (&dst)[32], int tau) {
        const float* krow = K + ((size_t)b * S_ + sbase + tau * 16 + sl) * O_ + fr * 4;
#pragma unroll
        for (int k = 0; k < 8; ++k) {
            float4 q = *(const float4*)(krow + k * 64);
            dst[k * 4 + 0] = q.x; dst[k * 4 + 1] = q.y;
            dst[k * 4 + 2] = q.z; dst[k * 4 + 3] = q.w;
        }
    };
    auto process = [&](float (&cur)[32], float (&nxt)[32], int tau, bool pre) {
        int s = sbase + tau * 16 + sl;
        size_t srow = (size_t)b * S_ + s;
        int mk = mask[srow];
        if (pre) loadK(nxt, tau + 1);

        // phase A: row LSE over 16 lanes (uold=0, v=0 -> x = K)
        float M = -INFINITY;
#pragma unroll
        for (int i = 0; i < 32; ++i) M = fmaxf(M, cur[i]);
#pragma unroll
        for (int off = 1; off < 16; off <<= 1) M = fmaxf(M, __shfl_xor(M, off));
        float a = 0.f;
#pragma unroll
        for (int i = 0; i < 32; ++i) a += __expf(cur[i] - M);
#pragma unroll
        for (int off = 1; off < 16; off <<= 1) a += __shfl_xor(a, off);
        float unew = lg - (M + logf(a));
        if (!mk) unew = NEG_INF_;
        if (fr == 0) { u[srow] = unew; u1c[srow] = unew; }

        float c = unew;   // y = K + u1
        _Float16* zw = zh + srow * O_ + fr * 4;
#pragma unroll
        for (int k = 0; k < 8; ++k) {
            float y0 = cur[k * 4 + 0] + c, y1 = cur[k * 4 + 1] + c;
            float y2 = cur[k * 4 + 2] + c, y3 = cur[k * 4 + 3] + c;
            float4 q; q.x = y0; q.y = y1; q.z = y2; q.w = y3;
            *(float4*)&sy[sl * YST + fr * 4 + k * 64] = q;
            half4v hq;
            hq[0] = (_Float16)y0; hq[1] = (_Float16)y1;
            hq[2] = (_Float16)y2; hq[3] = (_Float16)y3;
            *(half4v*)(zw + k * 64) = hq;
        }
        __syncthreads();
#pragma unroll
        for (int h = 0; h < 2; ++h) {
            int o = t + h * 256;
            float q[16];
            float m = -INFINITY;
#pragma unroll
            for (int r = 0; r < 16; ++r) { q[r] = sy[r * YST + o]; m = fmaxf(m, q[r]); }
            float aa = 0.f;
#pragma unroll
            for (int r = 0; r < 16; ++r) aa += __expf(q[r] - m);
            float Mo = h ? Mc1 : Mc0, Ao = h ? Ac1 : Ac0;
            float nm = fmaxf(Mo, m);
            Ao = Ao * __expf(Mo - nm) + aa * __expf(m - nm);
            if (h) { Mc1 = nm; Ac1 = Ao; } else { Mc0 = nm; Ac0 = Ao; }
        }
        __syncthreads();
    };
    loadK(bufA, 0);
    process(bufA, bufB, 0, true);
    process(bufB, bufA, 1, true);
    process(bufA, bufB, 2, true);
    process(bufB, bufA, 3, false);

    float2* cout = colma + ((size_t)b * 64 + blockIdx.x) * O_;
    {
        float2 r0; r0.x = Mc0; r0.y = Ac0; cout[t] = r0;
        float2 r1; r1.x = Mc1; r1.y = Ac1; cout[t + 256] = r1;
    }
}

// iterations 2..10: read fp16 z; x = z + (uold - u1) + v_old. Same guarded phases.
__global__ __launch_bounds__(256) void sink_late(const _Float16* __restrict__ zh,
                                                 const float* __restrict__ vin,
                                                 float* __restrict__ u,
                                                 const float* __restrict__ u1c,
                                                 float2* __restrict__ colma,
                                                 const int* __restrict__ mask,
                                                 const float* __restrict__ loga) {
    __shared__ float sv[O_];
    __shared__ float sy[16 * YST];
    int b = blockIdx.y;
    int t = threadIdx.x, fr = t & 15, sl = t >> 4;
    for (int i = t; i < O_; i += 256) sv[i] = vin[b * O_ + i];
    __syncthreads();
    int sbase = blockIdx.x * 64;
    float lg = loga[b];
    float Mc0 = -INFINITY, Ac0 = 0.f, Mc1 = -INFINITY, Ac1 = 0.f;

    float bufA[32], bufB[32];
    auto loadZ = [&](float (&dst)[32], int tau) {
        const _Float16* zrow = zh + ((size_t)b * S_ + sbase + tau * 16 + sl) * O_ + fr * 4;
#pragma unroll
        for (int k = 0; k < 8; ++k) {
            half4v q = *(const half4v*)(zrow + k * 64);
            // clamp -inf (masked rows / deep-negative) back to finite NEG_INF_
            dst[k * 4 + 0] = fmaxf((float)q[0], NEG_INF_);
            dst[k * 4 + 1] = fmaxf((float)q[1], NEG_INF_);
            dst[k * 4 + 2] = fmaxf((float)q[2], NEG_INF_);
            dst[k * 4 + 3] = fmaxf((float)q[3], NEG_INF_);
        }
    };
    auto process = [&](float (&cur)[32], float (&nxt)[32], int tau, bool pre) {
        int s = sbase + tau * 16 + sl;
        size_t srow = (size_t)b * S_ + s;
        float uold = u[srow];
        float du = uold - u1c[srow];
        int mk = mask[srow];
        if (pre) loadZ(nxt, tau + 1);

        float xv[32];
#pragma unroll
        for (int k = 0; k < 8; ++k) {
            float4 vvq = *(const float4*)&sv[fr * 4 + k * 64];
            xv[k * 4 + 0] = cur[k * 4 + 0] + du + vvq.x;
            xv[k * 4 + 1] = cur[k * 4 + 1] + du + vvq.y;
            xv[k * 4 + 2] = cur[k * 4 + 2] + du + vvq.z;
            xv[k * 4 + 3] = cur[k * 4 + 3] + du + vvq.w;
        }
        // phase A: row LSE (max-guarded)
        float M = -INFINITY;
#pragma unroll
        for (int i = 0; i < 32; ++i) M = fmaxf(M, xv[i]);
#pragma unroll
        for (int off = 1; off < 16; off <<= 1) M = fmaxf(M, __shfl_xor(M, off));
        float a = 0.f;
#pragma unroll
        for (int i = 0; i < 32; ++i) a += __expf(xv[i] - M);
#pragma unroll
        for (int off = 1; off < 16; off <<= 1) a += __shfl_xor(a, off);
        float unew = lg - (M + logf(a));
        if (!mk) unew = NEG_INF_;
        if (fr == 0) u[srow] = unew;

        float c = unew - uold;
#pragma unroll
        for (int k = 0; k < 8; ++k) {
            float4 q;
            q.x = xv[k * 4 + 0] + c; q.y = xv[k * 4 + 1] + c;
            q.z = xv[k * 4 + 2] + c; q.w = xv[k * 4 + 3] + c;
            *(float4*)&sy[sl * YST + fr * 4 + k * 64] = q;
        }
        __syncthreads();
#pragma unroll
        for (int h = 0; h < 2; ++h) {
            int o = t + h * 256;
            float q[16];
            float m = -INFINITY;
#pragma unroll
            for (int r = 0; r < 16; ++r) { q[r] = sy[r * YST + o]; m = fmaxf(m, q[r]); }
            float aa = 0.f;
#pragma unroll
            for (int r = 0; r < 16; ++r) aa += __expf(q[r] - m);
            float Mo = h ? Mc1 : Mc0, Ao = h ? Ac1 : Ac0;
            float nm = fmaxf(Mo, m);
            Ao = Ao * __expf(Mo - nm) + aa * __expf(m - nm);
            if (h) { Mc1 = nm; Ac1 = Ao; } else { Mc0 = nm; Ac0 = Ao; }
        }
        __syncthreads();
    };
    loadZ(bufA, 0);
    process(bufA, bufB, 0, true);
    process(bufB, bufA, 1, true);
    process(bufA, bufB, 2, true);
    process(bufB, bufA, 3, false);

    float2* cout = colma + ((size_t)b * 64 + blockIdx.x) * O_;
    {
        float2 r0; r0.x = Mc0; r0.y = Ac0; cout[t] = r0;
        float2 r1; r1.x = Mc1; r1.y = Ac1; cout[t + 256] = r1;
    }
}

// final (tier A): out = 4096*exp(z + (u10-u1) + v10 - 100 d^2), LDS transpose
__global__ __launch_bounds__(256) void final_tr_z(const _Float16* __restrict__ zh,
                                                  const float* __restrict__ u,
                                                  const float* __restrict__ u1c,
                                                  const float* __restrict__ v,
                                                  float* __restrict__ out) {
    __shared__ float tile[64][65];
    __shared__ float sdu[64], svv[64];
    int b = blockIdx.z;
    int s0 = blockIdx.x * 64, o0 = blockIdx.y * 64;
    int t = threadIdx.x, fr = t & 15, rg = t >> 4;
    if (t < 64) sdu[t] = u[(size_t)b * S_ + s0 + t] - u1c[(size_t)b * S_ + s0 + t];
    else if (t < 128) svv[t - 64] = v[b * O_ + o0 + t - 64];
    __syncthreads();
#pragma unroll
    for (int p = 0; p < 4; ++p) {
        int sl = p * 16 + rg;
        int s = s0 + sl;
        half4v hx = *(const half4v*)(zh + ((size_t)b * S_ + s) * O_ + o0 + fr * 4);
        float du = sdu[sl];
        float sn = (float)s * (1.0f / S_);
#pragma unroll
        for (int c = 0; c < 4; ++c) {
            int ol = fr * 4 + c;
            float zf = fmaxf((float)hx[c], NEG_INF_);
            float d = sn - (float)(o0 + ol) * (1.0f / O_);
            tile[ol][sl] = 4096.0f * __expf(zf + du + svv[ol] - 100.0f * d * d);
        }
    }
    __syncthreads();
#pragma unroll
    for (int p = 0; p < 4; ++p) {
        int ol = p * 16 + rg;
        float4 y;
        y.x = tile[ol][fr * 4 + 0];
        y.y = tile[ol][fr * 4 + 1];
        y.z = tile[ol][fr * 4 + 2];
        y.w = tile[ol][fr * 4 + 3];
        *(float4*)(out + ((size_t)b * O_ + o0 + ol) * S_ + s0 + fr * 4) = y;
    }
}

// ================= TIER B (round-11 proven, f32 K all the way) =================

template <int FIRST>
__global__ __launch_bounds__(256) void sink_iter(const float* __restrict__ K,
                                                 const float* __restrict__ vin,
                                                 float* __restrict__ u,
                                                 float2* __restrict__ colma,
                                                 const int* __restrict__ mask,
                                                 const float* __restrict__ loga) {
    __shared__ float sv[O_];
    __shared__ float sy[16 * YST];
    int b = blockIdx.y;
    int t = threadIdx.x, fr = t & 15, sl = t >> 4;
    if (!FIRST) {
        for (int i = t; i < O_; i += 256) sv[i] = vin[b * O_ + i];
        __syncthreads();
    }
    int sbase = blockIdx.x * 64;
    float lg = loga[b];
    float Mc0 = -INFINITY, Ac0 = 0.f, Mc1 = -INFINITY, Ac1 = 0.f;

    float bufA[32], bufB[32];
    auto loadK = [&](float (&dst)[32], int tau) {
        const float* krow = K + ((size_t)b * S_ + sbase + tau * 16 + sl) * O_ + fr * 4;
#pragma unroll
        for (int k = 0; k < 8; ++k) {
            float4 q = *(const float4*)(krow + k * 64);
            dst[k * 4 + 0] = q.x; dst[k * 4 + 1] = q.y;
            dst[k * 4 + 2] = q.z; dst[k * 4 + 3] = q.w;
        }
    };
    auto process = [&](float (&cur)[32], float (&nxt)[32], int tau, bool pre) {
        int s = sbase + tau * 16 + sl;
        size_t srow = (size_t)b * S_ + s;
        float uold = FIRST ? 0.f : u[srow];
        int mk = mask[srow];
        if (pre) loadK(nxt, tau + 1);

        float xv[32];
        if (FIRST) {
#pragma unroll
            for (int i = 0; i < 32; ++i) xv[i] = cur[i];
        } else {
#pragma unroll
            for (int k = 0; k < 8; ++k) {
                float4 vvq = *(const float4*)&sv[fr * 4 + k * 64];
                xv[k * 4 + 0] = cur[k * 4 + 0] + uold + vvq.x;
                xv[k * 4 + 1] = cur[k * 4 + 1] + uold + vvq.y;
                xv[k * 4 + 2] = cur[k * 4 + 2] + uold + vvq.z;
                xv[k * 4 + 3] = cur[k * 4 + 3] + uold + vvq.w;
            }
        }
        float M = -INFINITY;
#pragma unroll
        for (int i = 0; i < 32; ++i) M = fmaxf(M, xv[i]);
#pragma unroll
        for (int off = 1; off < 16; off <<= 1) M = fmaxf(M, __shfl_xor(M, off));
        float a = 0.f;
#pragma unroll
        for (int i = 0; i < 32; ++i) a += __expf(xv[i] - M);
#pragma unroll
        for (int off = 1; off < 16; off <<= 1) a += __shfl_xor(a, off);
        float unew = lg - (M + logf(a));
        if (!mk) unew = NEG_INF_;
        if (fr == 0) u[srow] = unew;

        float c = unew - uold;
#pragma unroll
        for (int k = 0; k < 8; ++k) {
            float4 q;
            q.x = xv[k * 4 + 0] + c; q.y = xv[k * 4 + 1] + c;
            q.z = xv[k * 4 + 2] + c; q.w = xv[k * 4 + 3] + c;
            *(float4*)&sy[sl * YST + fr * 4 + k * 64] = q;
        }
        __syncthreads();
#pragma unroll
        for (int h = 0; h < 2; ++h) {
            int o = t + h * 256;
            float q[16];
            float m = -INFINITY;
#pragma unroll
            for (int r = 0; r < 16; ++r) { q[r] = sy[r * YST + o]; m = fmaxf(m, q[r]); }
            float aa = 0.f;
#pragma unroll
            for (int r = 0; r < 16; ++r) aa += __expf(q[r] - m);
            float Mo = h ? Mc1 : Mc0, Ao = h ? Ac1 : Ac0;
            float nm = fmaxf(Mo, m);
            Ao = Ao * __expf(Mo - nm) + aa * __expf(m - nm);
            if (h) { Mc1 = nm; Ac1 = Ao; } else { Mc0 = nm; Ac0 = Ao; }
        }
        __syncthreads();
    };
    loadK(bufA, 0);
    process(bufA, bufB, 0, true);
    process(bufB, bufA, 1, true);
    process(bufA, bufB, 2, true);
    process(bufB, bufA, 3, false);

    float2* cout = colma + ((size_t)b * 64 + blockIdx.x) * O_;
    {
        float2 r0; r0.x = Mc0; r0.y = Ac0; cout[t] = r0;
        float2 r1; r1.x = Mc1; r1.y = Ac1; cout[t + 256] = r1;
    }
}

// finalize v: merge 64 (m,a) chunks per column (log-space) -> v = -(M + log A)
__global__ __launch_bounds__(256) void finalize_v(const float2* __restrict__ colma,
                                                  float* __restrict__ v) {
    __shared__ float sm[4][64], sa[4][64];
    int b = blockIdx.y;
    int ol = threadIdx.x & 63, cg = threadIdx.x >> 6;
    int o = blockIdx.x * 64 + ol;
    const float2* cp = colma + (size_t)b * 64 * O_ + o;
    float M = -INFINITY, A = 0.f;
#pragma unroll 4
    for (int i = 0; i < 16; ++i) {
        float2 q = cp[(size_t)(cg * 16 + i) * O_];
        float nm = fmaxf(M, q.x);
        A = A * __expf(M - nm) + q.y * __expf(q.x - nm);
        M = nm;
    }
    sm[cg][ol] = M; sa[cg][ol] = A;
    __syncthreads();
    if (threadIdx.x < 64) {
        M = sm[0][ol]; A = sa[0][ol];
#pragma unroll
        for (int i = 1; i < 4; ++i) {
            float mi = sm[i][ol], ai = sa[i][ol];
            float nm = fmaxf(M, mi);
            A = A * __expf(M - nm) + ai * __expf(mi - nm);
            M = nm;
        }
        v[b * O_ + o] = -(M + logf(A));
    }
}

// final (tier B): out = 4096*exp(K + u + v - 100 d^2), LDS transpose
__global__ __launch_bounds__(256) void final_tr(const float* __restrict__ K,
                                                const float* __restrict__ u,
                                                const float* __restrict__ v,
                                                float* __restrict__ out) {
    __shared__ float tile[64][65];
    __shared__ float su[64], svv[64];
    int b = blockIdx.z;
    int s0 = blockIdx.x * 64, o0 = blockIdx.y * 64;
    int t = threadIdx.x, fr = t & 15, rg = t >> 4;
    if (t < 64) su[t] = u[(size_t)b * S_ + s0 + t];
    else if (t < 128) svv[t - 64] = v[b * O_ + o0 + t - 64];
    __syncthreads();
#pragma unroll
    for (int p = 0; p < 4; ++p) {
        int sl = p * 16 + rg;
        int s = s0 + sl;
        float4 x = *(const float4*)(K + ((size_t)b * S_ + s) * O_ + o0 + fr * 4);
        float us = su[sl];
        float sn = (float)s * (1.0f / S_);
        float xs[4] = {x.x, x.y, x.z, x.w};
#pragma unroll
        for (int c = 0; c < 4; ++c) {
            int ol = fr * 4 + c;
            float d = sn - (float)(o0 + ol) * (1.0f / O_);
            tile[ol][sl] = 4096.0f * __expf(xs[c] + us + svv[ol] - 100.0f * d * d);
        }
    }
    __syncthreads();
#pragma unroll
    for (int p = 0; p < 4; ++p) {
        int ol = p * 16 + rg;
        float4 y;
        y.x = tile[ol][fr * 4 + 0];
        y.y = tile[ol][fr * 4 + 1];
        y.z = tile[ol][fr * 4 + 2];
        y.w = tile[ol][fr * 4 + 3];
        *(float4*)(out + ((size_t)b * O_ + o0 + ol) * S_ + s0 + fr * 4) = y;
    }
}

// ================= FALLBACK PATH (round-3 proven, KT in d_out) =================

__global__ __launch_bounds__(256) void gemm_kt2(const unsigned short* __restrict__ in_hi,
                                                const unsigned short* __restrict__ in_lo,
                                                const unsigned short* __restrict__ tg_hi,
                                                const unsigned short* __restrict__ tg_lo,
                                                const float* __restrict__ iou,
                                                float* __restrict__ KT) {
    __shared__ float siou[64 * 65];
    int b = blockIdx.z;
    int s0 = blockIdx.x * 64;
    int o0 = blockIdx.y * 64;
    int t = threadIdx.x;
    {
        const float* ir = iou + ((size_t)b * S_ + s0 + (t >> 2)) * O_ + o0 + (t & 3) * 16;
        float4 q0 = ((const float4*)ir)[0];
        float4 q1 = ((const float4*)ir)[1];
        float4 q2 = ((const float4*)ir)[2];
        float4 q3 = ((const float4*)ir)[3];
        float* dst = &siou[(t >> 2) * 65 + (t & 3) * 16];
        dst[0]=q0.x; dst[1]=q0.y; dst[2]=q0.z; dst[3]=q0.w;
        dst[4]=q1.x; dst[5]=q1.y; dst[6]=q1.z; dst[7]=q1.w;
        dst[8]=q2.x; dst[9]=q2.y; dst[10]=q2.z; dst[11]=q2.w;
        dst[12]=q3.x; dst[13]=q3.y; dst[14]=q3.z; dst[15]=q3.w;
    }
    int w = t >> 6, lane = t & 63, fr = lane & 15, kg = lane >> 4;
    const unsigned short* ta_hi = tg_hi + ((size_t)b * O_ + o0 + w * 16 + fr) * D_;
    const unsigned short* ta_lo = tg_lo + ((size_t)b * O_ + o0 + w * 16 + fr) * D_;
    const unsigned short* ib_hi = in_hi + ((size_t)b * S_ + s0 + fr) * D_;
    const unsigned short* ib_lo = in_lo + ((size_t)b * S_ + s0 + fr) * D_;
    floatx4 acc[4];
#pragma unroll
    for (int st = 0; st < 4; ++st) acc[st] = (floatx4){0.f, 0.f, 0.f, 0.f};
#pragma unroll
    for (int kb = 0; kb < 4; ++kb) {
        int ko = kb * 32 + kg * 8;
        short8 ah = *(const short8*)(ta_hi + ko);
        short8 al2 = *(const short8*)(ta_lo + ko);
#pragma unroll
        for (int st = 0; st < 4; ++st) {
            short8 bh2 = *(const short8*)(ib_hi + (size_t)st * 16 * D_ + ko);
            short8 bl2 = *(const short8*)(ib_lo + (size_t)st * 16 * D_ + ko);
            acc[st] = __builtin_amdgcn_mfma_f32_16x16x32_bf16(al2, bh2, acc[st], 0, 0, 0);
            acc[st] = __builtin_amdgcn_mfma_f32_16x16x32_bf16(ah, bl2, acc[st], 0, 0, 0);
            acc[st] = __builtin_amdgcn_mfma_f32_16x16x32_bf16(ah, bh2, acc[st], 0, 0, 0);
        }
    }
    __syncthreads();
#pragma unroll
    for (int st = 0; st < 4; ++st) {
        int s = s0 + st * 16 + fr;
        float ds = (float)s * (1.0f / S_);
#pragma unroll
        for (int r = 0; r < 4; ++r) {
            int o = o0 + w * 16 + kg * 4 + r;
            float d = ds - (float)o * (1.0f / O_);
            float pf = __expf(-100.0f * d * d);
            float iouv = siou[(st * 16 + fr) * 65 + (w * 16 + kg * 4 + r)];
            KT[((size_t)b * O_ + o) * S_ + s] = pf * (acc[st][r] - iouv) * 10.0f;
        }
    }
}

__global__ __launch_bounds__(256) void row_update2(const float* __restrict__ KT,
                                                   const float* __restrict__ v,
                                                   float* __restrict__ u,
                                                   const int* __restrict__ mask,
                                                   const float* __restrict__ loga) {
    __shared__ float sv[O_];
    __shared__ float lm[4][128], la[4][128];
    int b = blockIdx.y;
    int s0 = blockIdx.x * 128;
    int t = threadIdx.x, lane = t & 63, w = t >> 6;
    for (int i = t; i < O_; i += 256) sv[i] = v[b * O_ + i];
    __syncthreads();
    const float* kt = KT + (size_t)b * O_ * S_ + s0 + lane * 2;
    float m0 = -INFINITY, m1 = -INFINITY, a0 = 0.f, a1 = 0.f;
    int ob = w * 128;
#pragma unroll 8
    for (int i = 0; i < 128; ++i) {
        int o = ob + i;
        float2 x2 = *(const float2*)(kt + (size_t)o * S_);
        float vo = sv[o];
        float x0 = x2.x + vo, x1 = x2.y + vo;
        if (x0 > m0) { a0 = a0 * __expf(m0 - x0) + 1.f; m0 = x0; } else a0 += __expf(x0 - m0);
        if (x1 > m1) { a1 = a1 * __expf(m1 - x1) + 1.f; m1 = x1; } else a1 += __expf(x1 - m1);
    }
    lm[w][lane * 2] = m0;     la[w][lane * 2] = a0;
    lm[w][lane * 2 + 1] = m1; la[w][lane * 2 + 1] = a1;
    __syncthreads();
    if (t < 128) {
        float M = lm[0][t], A = la[0][t];
#pragma unroll
        for (int i = 1; i < 4; ++i) {
            float mi = lm[i][t], ai = la[i][t];
            float nm = fmaxf(M, mi);
            A = A * __expf(M - nm) + ai * __expf(mi - nm);
            M = nm;
        }
        float lse = M + logf(A);
        size_t si = (size_t)b * S_ + s0 + t;
        u[si] = mask[si] ? (loga[b] - u[si] - lse) : NEG_INF_;
    }
}

template <int FIN>
__global__ __launch_bounds__(256) void col_update2(float* __restrict__ KT,
                                                   const float* __restrict__ u,
                                                   float* __restrict__ v) {
    __shared__ float red[8];
    int b = blockIdx.y, o = blockIdx.x;
    int t = threadIdx.x;
    float* kt = KT + ((size_t)b * O_ + o) * S_;
    const float* ub = u + (size_t)b * S_;
    float vold = v[b * O_ + o];
    float xs[16];
    float m = -INFINITY, a = 0.f;
#pragma unroll
    for (int k = 0; k < 4; ++k) {
        int s = k * 1024 + t * 4;
        float4 kx = *(const float4*)(kt + s);
        float4 ux = *(const float4*)(ub + s);
        float x0 = kx.x + ux.x, x1 = kx.y + ux.y, x2 = kx.z + ux.z, x3 = kx.w + ux.w;
        if (FIN) { xs[k*4] = x0; xs[k*4+1] = x1; xs[k*4+2] = x2; xs[k*4+3] = x3; }
        float cm = fmaxf(fmaxf(x0, x1), fmaxf(x2, x3));
        float nm = fmaxf(m, cm);
        a = a * __expf(m - nm) + __expf(x0 - nm) + __expf(x1 - nm)
                               + __expf(x2 - nm) + __expf(x3 - nm);
        m = nm;
    }
#pragma unroll
    for (int off = 1; off < 64; off <<= 1) {
        float mo = __shfl_xor(m, off), ao = __shfl_xor(a, off);
        float nm = fmaxf(m, mo);
        a = a * __expf(m - nm) + ao * __expf(mo - nm);
        m = nm;
    }
    int w = t >> 6;
    if ((t & 63) == 0) { red[w * 2] = m; red[w * 2 + 1] = a; }
    __syncthreads();
    float M = red[0], A = red[1];
#pragma unroll
    for (int i = 1; i < 4; ++i) {
        float mi = red[i * 2], ai = red[i * 2 + 1];
        float nm = fmaxf(M, mi);
        A = A * __expf(M - nm) + ai * __expf(mi - nm);
        M = nm;
    }
    float lse = M + logf(A);
    float vn = -vold - lse;
    if (t == 0) v[b * O_ + o] = vn;
    if (FIN) {
        float oo = (float)o * (1.0f / O_);
#pragma unroll
        for (int k = 0; k < 4; ++k) {
            int s = k * 1024 + t * 4;
            float4 r;
            float rr[4];
#pragma unroll
            for (int j = 0; j < 4; ++j) {
                float d = (float)(s + j) * (1.0f / S_) - oo;
                rr[j] = 4096.0f * __expf(xs[k * 4 + j] + vn - 100.0f * d * d);
            }
            r.x = rr[0]; r.y = rr[1]; r.z = rr[2]; r.w = rr[3];
            *(float4*)(kt + s) = r;
        }
    }
}

// ================= launch =================

extern "C" void kernel_launch(void* const* d_in, const int* in_sizes, int n_in,
                              void* d_out, int out_size, void* d_ws, size_t ws_size,
                              hipStream_t stream) {
    const float* input  = (const float*)d_in[0];
    const float* target = (const float*)d_in[1];
    const float* iou    = (const float*)d_in[2];
    const int*   mask   = (const int*)d_in[3];
    float* out = (float*)d_out;
    float* wsf = (float*)d_ws;

    const size_t N_IN = (size_t)B_ * S_ * D_;   // 8388608
    const size_t N_TG = (size_t)B_ * O_ * D_;   // 1048576
    const size_t NK   = (size_t)B_ * S_ * O_;   // 33554432

    float* u    = wsf;
    float* v    = u + (size_t)B_ * S_;
    float* loga = v + (size_t)B_ * O_;
    float* u1c  = loga + 16;
    float* Knat = u1c + (size_t)B_ * S_;
    char*  region = (char*)(Knat + NK);

    // splits (live only until gemm completes)
    unsigned short* f_in_hi = (unsigned short*)region;
    unsigned short* f_in_lo = f_in_hi + N_IN;
    unsigned short* f_tg_hi = f_in_lo + N_IN;
    unsigned short* f_tg_lo = f_tg_hi + N_TG;
    size_t need_B = (size_t)((char*)(f_tg_lo + N_TG) - (char*)d_ws);

    // tier-A overlay: colma then zh (both live from iter 1 on; splits dead)
    float2* colma = (float2*)region;
    _Float16* zh = (_Float16*)(colma + (size_t)B_ * 64 * O_);
    size_t need_A = (size_t)((char*)(zh + NK) - (char*)d_ws);
    if (need_A < need_B) need_A = need_B;   // splits must also fit

    // fallback layout (round-3)
    unsigned short* m_in_hi = (unsigned short*)(loga + 16);
    unsigned short* m_in_lo = m_in_hi + N_IN;
    unsigned short* m_tg_hi = m_in_lo + N_IN;
    unsigned short* m_tg_lo = m_tg_hi + N_TG;
    size_t need_mid = (size_t)((char*)(m_tg_lo + N_TG) - (char*)d_ws);

    init_kernel<<<B_, 256, 0, stream>>>(mask, u, v, loga);
    int n4A = (int)(N_IN / 4), n4B = (int)(N_TG / 4);

    if (ws_size >= need_A) {
        split_kernel<<<(n4A + n4B + 255) / 256, 256, 0, stream>>>(
            input, f_in_hi, f_in_lo, n4A, target, f_tg_hi, f_tg_lo, n4B);
        gemm_nat<<<dim3(S_ / 256, O_ / 64, B_), 256, 0, stream>>>(f_in_hi, f_in_lo, f_tg_hi, f_tg_lo, iou, Knat);
        sink_first_z<<<dim3(S_ / 64, B_), 256, 0, stream>>>(Knat, u, u1c, zh, colma, mask, loga);
        finalize_v<<<dim3(O_ / 64, B_), 256, 0, stream>>>(colma, v);
        for (int it = 1; it < MAX_ITER_; ++it) {
            sink_late<<<dim3(S_ / 64, B_), 256, 0, stream>>>(zh, v, u, u1c, colma, mask, loga);
            finalize_v<<<dim3(O_ / 64, B_), 256, 0, stream>>>(colma, v);
        }
        final_tr_z<<<dim3(S_ / 64, O_ / 64, B_), 256, 0, stream>>>(zh, u, u1c, v, out);
    } else if (ws_size >= need_B) {
        split_kernel<<<(n4A + n4B + 255) / 256, 256, 0, stream>>>(
            input, f_in_hi, f_in_lo, n4A, target, f_tg_hi, f_tg_lo, n4B);
        gemm_nat<<<dim3(S_ / 256, O_ / 64, B_), 256, 0, stream>>>(f_in_hi, f_in_lo, f_tg_hi, f_tg_lo, iou, Knat);
        for (int it = 0; it < MAX_ITER_; ++it) {
            if (it == 0)
                sink_iter<1><<<dim3(S_ / 64, B_), 256, 0, stream>>>(Knat, v, u, colma, mask, loga);
            else
                sink_iter<0><<<dim3(S_ / 64, B_), 256, 0, stream>>>(Knat, v, u, colma, mask, loga);
            finalize_v<<<dim3(O_ / 64, B_), 256, 0, stream>>>(colma, v);
        }
        final_tr<<<dim3(S_ / 64, O_ / 64, B_), 256, 0, stream>>>(Knat, u, v, out);
    } else if (ws_size >= need_mid) {
        split_kernel<<<(n4A + n4B + 255) / 256, 256, 0, stream>>>(
            input, m_in_hi, m_in_lo, n4A, target, m_tg_hi, m_tg_lo, n4B);
        gemm_kt2<<<dim3(S_ / 64, O_ / 64, B_), 256, 0, stream>>>(m_in_hi, m_in_lo, m_tg_hi, m_tg_lo, iou, out);
        for (int it = 0; it < MAX_ITER_; ++it) {
            row_update2<<<dim3(S_ / 128, B_), 256, 0, stream>>>(out, v, u, mask, loga);
            if (it < MAX_ITER_ - 1)
                col_update2<0><<<dim3(O_, B_), 256, 0, stream>>>(out, u, v);
            else
                col_update2<1><<<dim3(O_, B_), 256, 0, stream>>>(out, u, v);
        }
    }
}

// Round 15
// 466.996 us; speedup vs baseline: 1.1017x; 1.0443x over previous
//
#include <hip/hip_runtime.h>
#include <hip/hip_bf16.h>

#define B_ 16
#define S_ 4096
#define O_ 512
#define D_ 128
#define NEG_INF_ -1e8f
#define MAX_ITER_ 10
#define YST 513

typedef __attribute__((ext_vector_type(8))) short short8;
typedef __attribute__((ext_vector_type(4))) float floatx4;
typedef __attribute__((ext_vector_type(4))) unsigned short ushort4v;
typedef __attribute__((ext_vector_type(4))) _Float16 half4v;

__device__ inline unsigned short f32_to_bf16_rne(float x) {
    union { float f; unsigned int u; } c; c.f = x;
    unsigned int u = c.u;
    unsigned int r = (u + 0x7FFFu + ((u >> 16) & 1u)) >> 16;
    return (unsigned short)r;
}
__device__ inline float bf16_bits_to_f32(unsigned short h) {
    union { unsigned int u; float f; } c; c.u = ((unsigned int)h) << 16;
    return c.f;
}
// load 8 f32 and split into bf16 hi/lo fragments (same numerics as split_kernel)
__device__ inline void cvt8(const float* p, short8& hi, short8& lo) {
    float4 a = *(const float4*)p;
    float4 b = *(const float4*)(p + 4);
    float xs[8] = {a.x, a.y, a.z, a.w, b.x, b.y, b.z, b.w};
#pragma unroll
    for (int j = 0; j < 8; ++j) {
        unsigned short h = f32_to_bf16_rne(xs[j]);
        hi[j] = (short)h;
        lo[j] = (short)f32_to_bf16_rne(xs[j] - bf16_bits_to_f32(h));
    }
}

// ---------------- init: loga from mask, zero u,v ----------------
__global__ void init_kernel(const int* __restrict__ mask,
                            float* __restrict__ u, float* __restrict__ v,
                            float* __restrict__ loga) {
    __shared__ int sc[256];
    int b = blockIdx.x, t = threadIdx.x;
    int c = 0;
    for (int k = t; k < S_; k += 256) c += (mask[(size_t)b * S_ + k] != 0);
    sc[t] = c; __syncthreads();
    for (int st = 128; st > 0; st >>= 1) { if (t < st) sc[t] += sc[t + st]; __syncthreads(); }
    if (t == 0) loga[b] = logf((float)O_ / (float)sc[0]);
    for (int k = t; k < S_; k += 256) u[(size_t)b * S_ + k] = 0.f;
    for (int k = t; k < O_; k += 256) v[b * O_ + k] = 0.f;
}

// ---------------- pre-split f32 -> bf16 hi/lo (fallback tier only) ----------------
__global__ __launch_bounds__(256) void split_kernel(const float* __restrict__ srcA,
                                                    unsigned short* __restrict__ hiA,
                                                    unsigned short* __restrict__ loA, int n4A,
                                                    const float* __restrict__ srcB,
                                                    unsigned short* __restrict__ hiB,
                                                    unsigned short* __restrict__ loB, int n4B) {
    int i = blockIdx.x * 256 + threadIdx.x;
    const float* src; unsigned short* hi; unsigned short* lo;
    if (i < n4A) { src = srcA; hi = hiA; lo = loA; }
    else if (i < n4A + n4B) { i -= n4A; src = srcB; hi = hiB; lo = loB; }
    else return;
    float4 x = ((const float4*)src)[i];
    float xs[4] = {x.x, x.y, x.z, x.w};
    ushort4v h, l;
#pragma unroll
    for (int j = 0; j < 4; ++j) {
        unsigned short hh = f32_to_bf16_rne(xs[j]);
        float rem = xs[j] - bf16_bits_to_f32(hh);
        h[j] = hh; l[j] = f32_to_bf16_rne(rem);
    }
    ((ushort4v*)hi)[i] = h;
    ((ushort4v*)lo)[i] = l;
}

// ================= gemm: 256s x 64o per block, f32 inputs split IN-REGISTER =================
// A=target (o rows), B=input (s cols): C row=o (kg*4+r contiguous), col=s.
// Same VMEM count as the bf16-split version (4B/elem either way); conversion
// (~1.5k VALU cyc/wave) hides under MFMA. Saves the split kernel + 57MB ws traffic.
__global__ __launch_bounds__(256) void gemm_nat(const float* __restrict__ input,
                                                const float* __restrict__ target,
                                                const float* __restrict__ iou,
                                                float* __restrict__ K) {
    int b = blockIdx.z;
    int s0 = blockIdx.x * 256;
    int o0 = blockIdx.y * 64;
    int t = threadIdx.x, wid = t >> 6, lane = t & 63, fr = lane & 15, kg = lane >> 4;

    const float* irow = input  + ((size_t)b * S_ + s0 + wid * 64 + fr) * D_;
    const float* trow = target + ((size_t)b * O_ + o0 + fr) * D_;

    floatx4 acc[4][4];
#pragma unroll
    for (int i = 0; i < 4; ++i)
#pragma unroll
        for (int j = 0; j < 4; ++j) acc[i][j] = (floatx4){0.f, 0.f, 0.f, 0.f};

#pragma unroll
    for (int kb = 0; kb < 4; ++kb) {
        int ko = kb * 32 + kg * 8;
        short8 T_h[4], T_l[4];
#pragma unroll
        for (int j = 0; j < 4; ++j)
            cvt8(trow + (size_t)j * 16 * D_ + ko, T_h[j], T_l[j]);
#pragma unroll
        for (int i = 0; i < 4; ++i) {
            short8 I_h, I_l;
            cvt8(irow + (size_t)i * 16 * D_ + ko, I_h, I_l);
#pragma unroll
            for (int j = 0; j < 4; ++j) {
                acc[i][j] = __builtin_amdgcn_mfma_f32_16x16x32_bf16(T_l[j], I_h, acc[i][j], 0, 0, 0);
                acc[i][j] = __builtin_amdgcn_mfma_f32_16x16x32_bf16(T_h[j], I_l, acc[i][j], 0, 0, 0);
                acc[i][j] = __builtin_amdgcn_mfma_f32_16x16x32_bf16(T_h[j], I_h, acc[i][j], 0, 0, 0);
            }
        }
    }

#pragma unroll
    for (int i = 0; i < 4; ++i) {
        int s = s0 + wid * 64 + i * 16 + fr;
        float sn = (float)s * (1.0f / S_);
        size_t rowb = ((size_t)b * S_ + s) * O_;
#pragma unroll
        for (int j = 0; j < 4; ++j) {
            int ob = o0 + j * 16 + kg * 4;
            float4 iv = *(const float4*)(iou + rowb + ob);
            float ivs[4] = {iv.x, iv.y, iv.z, iv.w};
            float tmp[4];
#pragma unroll
            for (int r = 0; r < 4; ++r) {
                float d = sn - (float)(ob + r) * (1.0f / O_);
                float pf = __expf(-100.0f * d * d);
                tmp[r] = pf * (acc[i][j][r] - ivs[r]) * 10.0f;
            }
            float4 q; q.x = tmp[0]; q.y = tmp[1]; q.z = tmp[2]; q.w = tmp[3];
            *(float4*)(K + rowb + ob) = q;
        }
    }
}

// ================= TIER A: fp16 shadow z = K + u1 =================

__global__ __launch_bounds__(256) void sink_first_z(const float* __restrict__ K,
                                                    float* __restrict__ u,
                                                    float* __restrict__ u1c,
                                                    _Float16* __restrict__ zh,
                                                    float2* __restrict__ colma,
                                                    const int* __restrict__ mask,
                                                    const float* __restrict__ loga) {
    __shared__ float sy[16 * YST];
    int b = blockIdx.y;
    int t = threadIdx.x, fr = t & 15, sl = t >> 4;
    int sbase = blockIdx.x * 64;
    float lg = loga[b];
    float Mc0 = -INFINITY, Ac0 = 0.f, Mc1 = -INFINITY, Ac1 = 0.f;

    float bufA[32], bufB[32];
    auto loadK = [&](float (&dst)[32], int tau) {
        const float* krow = K + ((size_t)b * S_ + sbase + tau * 16 + sl) * O_ + fr * 4;
#pragma unroll
        for (int k = 0; k < 8; ++k) {
            float4 q = *(const float4*)(krow + k * 64);
            dst[k * 4 + 0] = q.x; dst[k * 4 + 1] = q.y;
            dst[k * 4 + 2] = q.z; dst[k * 4 + 3] = q.w;
        }
    };
    auto process = [&](float (&cur)[32], float (&nxt)[32], int tau, bool pre) {
        int s = sbase + tau * 16 + sl;
        size_t srow = (size_t)b * S_ + s;
        int mk = mask[srow];
        if (pre) loadK(nxt, tau + 1);

        float M = -INFINITY;
#pragma unroll
        for (int i = 0; i < 32; ++i) M = fmaxf(M, cur[i]);
#pragma unroll
        for (int off = 1; off < 16; off <<= 1) M = fmaxf(M, __shfl_xor(M, off));
        float a = 0.f;
#pragma unroll
        for (int i = 0; i < 32; ++i) a += __expf(cur[i] - M);
#pragma unroll
        for (int off = 1; off < 16; off <<= 1) a += __shfl_xor(a, off);
        float unew = lg - (M + logf(a));
        if (!mk) unew = NEG_INF_;
        if (fr == 0) { u[srow] = unew; u1c[srow] = unew; }

        float c = unew;   // y = K + u1
        _Float16* zw = zh + srow * O_ + fr * 4;
#pragma unroll
        for (int k = 0; k < 8; ++k) {
            float y0 = cur[k * 4 + 0] + c, y1 = cur[k * 4 + 1] + c;
            float y2 = cur[k * 4 + 2] + c, y3 = cur[k * 4 + 3] + c;
            float4 q; q.x = y0; q.y = y1; q.z = y2; q.w = y3;
            *(float4*)&sy[sl * YST + fr * 4 + k * 64] = q;
            half4v hq;
            hq[0] = (_Float16)y0; hq[1] = (_Float16)y1;
            hq[2] = (_Float16)y2; hq[3] = (_Float16)y3;
            *(half4v*)(zw + k * 64) = hq;
        }
        __syncthreads();
#pragma unroll
        for (int h = 0; h < 2; ++h) {
            int o = t + h * 256;
            float q[16];
            float m = -INFINITY;
#pragma unroll
            for (int r = 0; r < 16; ++r) { q[r] = sy[r * YST + o]; m = fmaxf(m, q[r]); }
            float aa = 0.f;
#pragma unroll
            for (int r = 0; r < 16; ++r) aa += __expf(q[r] - m);
            float Mo = h ? Mc1 : Mc0, Ao = h ? Ac1 : Ac0;
            float nm = fmaxf(Mo, m);
            Ao = Ao * __expf(Mo - nm) + aa * __expf(m - nm);
            if (h) { Mc1 = nm; Ac1 = Ao; } else { Mc0 = nm; Ac0 = Ao; }
        }
        __syncthreads();
    };
    loadK(bufA, 0);
    process(bufA, bufB, 0, true);
    process(bufB, bufA, 1, true);
    process(bufA, bufB, 2, true);
    process(bufB, bufA, 3, false);

    float2* cout = colma + ((size_t)b * 64 + blockIdx.x) * O_;
    {
        float2 r0; r0.x = Mc0; r0.y = Ac0; cout[t] = r0;
        float2 r1; r1.x = Mc1; r1.y = Ac1; cout[t + 256] = r1;
    }
}

__global__ __launch_bounds__(256) void sink_late(const _Float16* __restrict__ zh,
                                                 const float* __restrict__ vin,
                                                 float* __restrict__ u,
                                                 const float* __restrict__ u1c,
                                                 float2* __restrict__ colma,
                                                 const int* __restrict__ mask,
                                                 const float* __restrict__ loga) {
    __shared__ float sv[O_];
    __shared__ float sy[16 * YST];
    int b = blockIdx.y;
    int t = threadIdx.x, fr = t & 15, sl = t >> 4;
    for (int i = t; i < O_; i += 256) sv[i] = vin[b * O_ + i];
    __syncthreads();
    int sbase = blockIdx.x * 64;
    float lg = loga[b];
    float Mc0 = -INFINITY, Ac0 = 0.f, Mc1 = -INFINITY, Ac1 = 0.f;

    float bufA[32], bufB[32];
    auto loadZ = [&](float (&dst)[32], int tau) {
        const _Float16* zrow = zh + ((size_t)b * S_ + sbase + tau * 16 + sl) * O_ + fr * 4;
#pragma unroll
        for (int k = 0; k < 8; ++k) {
            half4v q = *(const half4v*)(zrow + k * 64);
            dst[k * 4 + 0] = fmaxf((float)q[0], NEG_INF_);
            dst[k * 4 + 1] = fmaxf((float)q[1], NEG_INF_);
            dst[k * 4 + 2] = fmaxf((float)q[2], NEG_INF_);
            dst[k * 4 + 3] = fmaxf((float)q[3], NEG_INF_);
        }
    };
    auto process = [&](float (&cur)[32], float (&nxt)[32], int tau, bool pre) {
        int s = sbase + tau * 16 + sl;
        size_t srow = (size_t)b * S_ + s;
        float uold = u[srow];
        float du = uold - u1c[srow];
        int mk = mask[srow];
        if (pre) loadZ(nxt, tau + 1);

        float xv[32];
#pragma unroll
        for (int k = 0; k < 8; ++k) {
            float4 vvq = *(const float4*)&sv[fr * 4 + k * 64];
            xv[k * 4 + 0] = cur[k * 4 + 0] + du + vvq.x;
            xv[k * 4 + 1] = cur[k * 4 + 1] + du + vvq.y;
            xv[k * 4 + 2] = cur[k * 4 + 2] + du + vvq.z;
            xv[k * 4 + 3] = cur[k * 4 + 3] + du + vvq.w;
        }
        float M = -INFINITY;
#pragma unroll
        for (int i = 0; i < 32; ++i) M = fmaxf(M, xv[i]);
#pragma unroll
        for (int off = 1; off < 16; off <<= 1) M = fmaxf(M, __shfl_xor(M, off));
        float a = 0.f;
#pragma unroll
        for (int i = 0; i < 32; ++i) a += __expf(xv[i] - M);
#pragma unroll
        for (int off = 1; off < 16; off <<= 1) a += __shfl_xor(a, off);
        float unew = lg - (M + logf(a));
        if (!mk) unew = NEG_INF_;
        if (fr == 0) u[srow] = unew;

        float c = unew - uold;
#pragma unroll
        for (int k = 0; k < 8; ++k) {
            float4 q;
            q.x = xv[k * 4 + 0] + c; q.y = xv[k * 4 + 1] + c;
            q.z = xv[k * 4 + 2] + c; q.w = xv[k * 4 + 3] + c;
            *(float4*)&sy[sl * YST + fr * 4 + k * 64] = q;
        }
        __syncthreads();
#pragma unroll
        for (int h = 0; h < 2; ++h) {
            int o = t + h * 256;
            float q[16];
            float m = -INFINITY;
#pragma unroll
            for (int r = 0; r < 16; ++r) { q[r] = sy[r * YST + o]; m = fmaxf(m, q[r]); }
            float aa = 0.f;
#pragma unroll
            for (int r = 0; r < 16; ++r) aa += __expf(q[r] - m);
            float Mo = h ? Mc1 : Mc0, Ao = h ? Ac1 : Ac0;
            float nm = fmaxf(Mo, m);
            Ao = Ao * __expf(Mo - nm) + aa * __expf(m - nm);
            if (h) { Mc1 = nm; Ac1 = Ao; } else { Mc0 = nm; Ac0 = Ao; }
        }
        __syncthreads();
    };
    loadZ(bufA, 0);
    process(bufA, bufB, 0, true);
    process(bufB, bufA, 1, true);
    process(bufA, bufB, 2, true);
    process(bufB, bufA, 3, false);

    float2* cout = colma + ((size_t)b * 64 + blockIdx.x) * O_;
    {
        float2 r0; r0.x = Mc0; r0.y = Ac0; cout[t] = r0;
        float2 r1; r1.x = Mc1; r1.y = Ac1; cout[t + 256] = r1;
    }
}

__global__ __launch_bounds__(256) void final_tr_z(const _Float16* __restrict__ zh,
                                                  const float* __restrict__ u,
                                                  const float* __restrict__ u1c,
                                                  const float* __restrict__ v,
                                                  float* __restrict__ out) {
    __shared__ float tile[64][65];
    __shared__ float sdu[64], svv[64];
    int b = blockIdx.z;
    int s0 = blockIdx.x * 64, o0 = blockIdx.y * 64;
    int t = threadIdx.x, fr = t & 15, rg = t >> 4;
    if (t < 64) sdu[t] = u[(size_t)b * S_ + s0 + t] - u1c[(size_t)b * S_ + s0 + t];
    else if (t < 128) svv[t - 64] = v[b * O_ + o0 + t - 64];
    __syncthreads();
#pragma unroll
    for (int p = 0; p < 4; ++p) {
        int sl = p * 16 + rg;
        int s = s0 + sl;
        half4v hx = *(const half4v*)(zh + ((size_t)b * S_ + s) * O_ + o0 + fr * 4);
        float du = sdu[sl];
        float sn = (float)s * (1.0f / S_);
#pragma unroll
        for (int c = 0; c < 4; ++c) {
            int ol = fr * 4 + c;
            float zf = fmaxf((float)hx[c], NEG_INF_);
            float d = sn - (float)(o0 + ol) * (1.0f / O_);
            tile[ol][sl] = 4096.0f * __expf(zf + du + svv[ol] - 100.0f * d * d);
        }
    }
    __syncthreads();
#pragma unroll
    for (int p = 0; p < 4; ++p) {
        int ol = p * 16 + rg;
        float4 y;
        y.x = tile[ol][fr * 4 + 0];
        y.y = tile[ol][fr * 4 + 1];
        y.z = tile[ol][fr * 4 + 2];
        y.w = tile[ol][fr * 4 + 3];
        *(float4*)(out + ((size_t)b * O_ + o0 + ol) * S_ + s0 + fr * 4) = y;
    }
}

// ================= TIER B (f32 K all the way) =================

template <int FIRST>
__global__ __launch_bounds__(256) void sink_iter(const float* __restrict__ K,
                                                 const float* __restrict__ vin,
                                                 float* __restrict__ u,
                                                 float2* __restrict__ colma,
                                                 const int* __restrict__ mask,
                                                 const float* __restrict__ loga) {
    __shared__ float sv[O_];
    __shared__ float sy[16 * YST];
    int b = blockIdx.y;
    int t = threadIdx.x, fr = t & 15, sl = t >> 4;
    if (!FIRST) {
        for (int i = t; i < O_; i += 256) sv[i] = vin[b * O_ + i];
        __syncthreads();
    }
    int sbase = blockIdx.x * 64;
    float lg = loga[b];
    float Mc0 = -INFINITY, Ac0 = 0.f, Mc1 = -INFINITY, Ac1 = 0.f;

    float bufA[32], bufB[32];
    auto loadK = [&](float (&dst)[32], int tau) {
        const float* krow = K + ((size_t)b * S_ + sbase + tau * 16 + sl) * O_ + fr * 4;
#pragma unroll
        for (int k = 0; k < 8; ++k) {
            float4 q = *(const float4*)(krow + k * 64);
            dst[k * 4 + 0] = q.x; dst[k * 4 + 1] = q.y;
            dst[k * 4 + 2] = q.z; dst[k * 4 + 3] = q.w;
        }
    };
    auto process = [&](float (&cur)[32], float (&nxt)[32], int tau, bool pre) {
        int s = sbase + tau * 16 + sl;
        size_t srow = (size_t)b * S_ + s;
        float uold = FIRST ? 0.f : u[srow];
        int mk = mask[srow];
        if (pre) loadK(nxt, tau + 1);

        float xv[32];
        if (FIRST) {
#pragma unroll
            for (int i = 0; i < 32; ++i) xv[i] = cur[i];
        } else {
#pragma unroll
            for (int k = 0; k < 8; ++k) {
                float4 vvq = *(const float4*)&sv[fr * 4 + k * 64];
                xv[k * 4 + 0] = cur[k * 4 + 0] + uold + vvq.x;
                xv[k * 4 + 1] = cur[k * 4 + 1] + uold + vvq.y;
                xv[k * 4 + 2] = cur[k * 4 + 2] + uold + vvq.z;
                xv[k * 4 + 3] = cur[k * 4 + 3] + uold + vvq.w;
            }
        }
        float M = -INFINITY;
#pragma unroll
        for (int i = 0; i < 32; ++i) M = fmaxf(M, xv[i]);
#pragma unroll
        for (int off = 1; off < 16; off <<= 1) M = fmaxf(M, __shfl_xor(M, off));
        float a = 0.f;
#pragma unroll
        for (int i = 0; i < 32; ++i) a += __expf(xv[i] - M);
#pragma unroll
        for (int off = 1; off < 16; off <<= 1) a += __shfl_xor(a, off);
        float unew = lg - (M + logf(a));
        if (!mk) unew = NEG_INF_;
        if (fr == 0) u[srow] = unew;

        float c = unew - uold;
#pragma unroll
        for (int k = 0; k < 8; ++k) {
            float4 q;
            q.x = xv[k * 4 + 0] + c; q.y = xv[k * 4 + 1] + c;
            q.z = xv[k * 4 + 2] + c; q.w = xv[k * 4 + 3] + c;
            *(float4*)&sy[sl * YST + fr * 4 + k * 64] = q;
        }
        __syncthreads();
#pragma unroll
        for (int h = 0; h < 2; ++h) {
            int o = t + h * 256;
            float q[16];
            float m = -INFINITY;
#pragma unroll
            for (int r = 0; r < 16; ++r) { q[r] = sy[r * YST + o]; m = fmaxf(m, q[r]); }
            float aa = 0.f;
#pragma unroll
            for (int r = 0; r < 16; ++r) aa += __expf(q[r] - m);
            float Mo = h ? Mc1 : Mc0, Ao = h ? Ac1 : Ac0;
            float nm = fmaxf(Mo, m);
            Ao = Ao * __expf(Mo - nm) + aa * __expf(m - nm);
            if (h) { Mc1 = nm; Ac1 = Ao; } else { Mc0 = nm; Ac0 = Ao; }
        }
        __syncthreads();
    };
    loadK(bufA, 0);
    process(bufA, bufB, 0, true);
    process(bufB, bufA, 1, true);
    process(bufA, bufB, 2, true);
    process(bufB, bufA, 3, false);

    float2* cout = colma + ((size_t)b * 64 + blockIdx.x) * O_;
    {
        float2 r0; r0.x = Mc0; r0.y = Ac0; cout[t] = r0;
        float2 r1; r1.x = Mc1; r1.y = Ac1; cout[t + 256] = r1;
    }
}

__global__ __launch_bounds__(256) void finalize_v(const float2* __restrict__ colma,
                                                  float* __restrict__ v) {
    __shared__ float sm[4][64], sa[4][64];
    int b = blockIdx.y;
    int ol = threadIdx.x & 63, cg = threadIdx.x >> 6;
    int o = blockIdx.x * 64 + ol;
    const float2* cp = colma + (size_t)b * 64 * O_ + o;
    float M = -INFINITY, A = 0.f;
#pragma unroll 4
    for (int i = 0; i < 16; ++i) {
        float2 q = cp[(size_t)(cg * 16 + i) * O_];
        float nm = fmaxf(M, q.x);
        A = A * __expf(M - nm) + q.y * __expf(q.x - nm);
        M = nm;
    }
    sm[cg][ol] = M; sa[cg][ol] = A;
    __syncthreads();
    if (threadIdx.x < 64) {
        M = sm[0][ol]; A = sa[0][ol];
#pragma unroll
        for (int i = 1; i < 4; ++i) {
            float mi = sm[i][ol], ai = sa[i][ol];
            float nm = fmaxf(M, mi);
            A = A * __expf(M - nm) + ai * __expf(mi - nm);
            M = nm;
        }
        v[b * O_ + o] = -(M + logf(A));
    }
}

__global__ __launch_bounds__(256) void final_tr(const float* __restrict__ K,
                                                const float* __restrict__ u,
                                                const float* __restrict__ v,
                                                float* __restrict__ out) {
    __shared__ float tile[64][65];
    __shared__ float su[64], svv[64];
    int b = blockIdx.z;
    int s0 = blockIdx.x * 64, o0 = blockIdx.y * 64;
    int t = threadIdx.x, fr = t & 15, rg = t >> 4;
    if (t < 64) su[t] = u[(size_t)b * S_ + s0 + t];
    else if (t < 128) svv[t - 64] = v[b * O_ + o0 + t - 64];
    __syncthreads();
#pragma unroll
    for (int p = 0; p < 4; ++p) {
        int sl = p * 16 + rg;
        int s = s0 + sl;
        float4 x = *(const float4*)(K + ((size_t)b * S_ + s) * O_ + o0 + fr * 4);
        float us = su[sl];
        float sn = (float)s * (1.0f / S_);
        float xs[4] = {x.x, x.y, x.z, x.w};
#pragma unroll
        for (int c = 0; c < 4; ++c) {
            int ol = fr * 4 + c;
            float d = sn - (float)(o0 + ol) * (1.0f / O_);
            tile[ol][sl] = 4096.0f * __expf(xs[c] + us + svv[ol] - 100.0f * d * d);
        }
    }
    __syncthreads();
#pragma unroll
    for (int p = 0; p < 4; ++p) {
        int ol = p * 16 + rg;
        float4 y;
        y.x = tile[ol][fr * 4 + 0];
        y.y = tile[ol][fr * 4 + 1];
        y.z = tile[ol][fr * 4 + 2];
        y.w = tile[ol][fr * 4 + 3];
        *(float4*)(out + ((size_t)b * O_ + o0 + ol) * S_ + s0 + fr * 4) = y;
    }
}

// ================= FALLBACK PATH (round-3 proven, KT in d_out) =================

__global__ __launch_bounds__(256) void gemm_kt2(const unsigned short* __restrict__ in_hi,
                                                const unsigned short* __restrict__ in_lo,
                                                const unsigned short* __restrict__ tg_hi,
                                                const unsigned short* __restrict__ tg_lo,
                                                const float* __restrict__ iou,
                                                float* __restrict__ KT) {
    __shared__ float siou[64 * 65];
    int b = blockIdx.z;
    int s0 = blockIdx.x * 64;
    int o0 = blockIdx.y * 64;
    int t = threadIdx.x;
    {
        const float* ir = iou + ((size_t)b * S_ + s0 + (t >> 2)) * O_ + o0 + (t & 3) * 16;
        float4 q0 = ((const float4*)ir)[0];
        float4 q1 = ((const float4*)ir)[1];
        float4 q2 = ((const float4*)ir)[2];
        float4 q3 = ((const float4*)ir)[3];
        float* dst = &siou[(t >> 2) * 65 + (t & 3) * 16];
        dst[0]=q0.x; dst[1]=q0.y; dst[2]=q0.z; dst[3]=q0.w;
        dst[4]=q1.x; dst[5]=q1.y; dst[6]=q1.z; dst[7]=q1.w;
        dst[8]=q2.x; dst[9]=q2.y; dst[10]=q2.z; dst[11]=q2.w;
        dst[12]=q3.x; dst[13]=q3.y; dst[14]=q3.z; dst[15]=q3.w;
    }
    int w = t >> 6, lane = t & 63, fr = lane & 15, kg = lane >> 4;
    const unsigned short* ta_hi = tg_hi + ((size_t)b * O_ + o0 + w * 16 + fr) * D_;
    const unsigned short* ta_lo = tg_lo + ((size_t)b * O_ + o0 + w * 16 + fr) * D_;
    const unsigned short* ib_hi = in_hi + ((size_t)b * S_ + s0 + fr) * D_;
    const unsigned short* ib_lo = in_lo + ((size_t)b * S_ + s0 + fr) * D_;
    floatx4 acc[4];
#pragma unroll
    for (int st = 0; st < 4; ++st) acc[st] = (floatx4){0.f, 0.f, 0.f, 0.f};
#pragma unroll
    for (int kb = 0; kb < 4; ++kb) {
        int ko = kb * 32 + kg * 8;
        short8 ah = *(const short8*)(ta_hi + ko);
        short8 al2 = *(const short8*)(ta_lo + ko);
#pragma unroll
        for (int st = 0; st < 4; ++st) {
            short8 bh2 = *(const short8*)(ib_hi + (size_t)st * 16 * D_ + ko);
            short8 bl2 = *(const short8*)(ib_lo + (size_t)st * 16 * D_ + ko);
            acc[st] = __builtin_amdgcn_mfma_f32_16x16x32_bf16(al2, bh2, acc[st], 0, 0, 0);
            acc[st] = __builtin_amdgcn_mfma_f32_16x16x32_bf16(ah, bl2, acc[st], 0, 0, 0);
            acc[st] = __builtin_amdgcn_mfma_f32_16x16x32_bf16(ah, bh2, acc[st], 0, 0, 0);
        }
    }
    __syncthreads();
#pragma unroll
    for (int st = 0; st < 4; ++st) {
        int s = s0 + st * 16 + fr;
        float ds = (float)s * (1.0f / S_);
#pragma unroll
        for (int r = 0; r < 4; ++r) {
            int o = o0 + w * 16 + kg * 4 + r;
            float d = ds - (float)o * (1.0f / O_);
            float pf = __expf(-100.0f * d * d);
            float iouv = siou[(st * 16 + fr) * 65 + (w * 16 + kg * 4 + r)];
            KT[((size_t)b * O_ + o) * S_ + s] = pf * (acc[st][r] - iouv) * 10.0f;
        }
    }
}

__global__ __launch_bounds__(256) void row_update2(const float* __restrict__ KT,
                                                   const float* __restrict__ v,
                                                   float* __restrict__ u,
                                                   const int* __restrict__ mask,
                                                   const float* __restrict__ loga) {
    __shared__ float sv[O_];
    __shared__ float lm[4][128], la[4][128];
    int b = blockIdx.y;
    int s0 = blockIdx.x * 128;
    int t = threadIdx.x, lane = t & 63, w = t >> 6;
    for (int i = t; i < O_; i += 256) sv[i] = v[b * O_ + i];
    __syncthreads();
    const float* kt = KT + (size_t)b * O_ * S_ + s0 + lane * 2;
    float m0 = -INFINITY, m1 = -INFINITY, a0 = 0.f, a1 = 0.f;
    int ob = w * 128;
#pragma unroll 8
    for (int i = 0; i < 128; ++i) {
        int o = ob + i;
        float2 x2 = *(const float2*)(kt + (size_t)o * S_);
        float vo = sv[o];
        float x0 = x2.x + vo, x1 = x2.y + vo;
        if (x0 > m0) { a0 = a0 * __expf(m0 - x0) + 1.f; m0 = x0; } else a0 += __expf(x0 - m0);
        if (x1 > m1) { a1 = a1 * __expf(m1 - x1) + 1.f; m1 = x1; } else a1 += __expf(x1 - m1);
    }
    lm[w][lane * 2] = m0;     la[w][lane * 2] = a0;
    lm[w][lane * 2 + 1] = m1; la[w][lane * 2 + 1] = a1;
    __syncthreads();
    if (t < 128) {
        float M = lm[0][t], A = la[0][t];
#pragma unroll
        for (int i = 1; i < 4; ++i) {
            float mi = lm[i][t], ai = la[i][t];
            float nm = fmaxf(M, mi);
            A = A * __expf(M - nm) + ai * __expf(mi - nm);
            M = nm;
        }
        float lse = M + logf(A);
        size_t si = (size_t)b * S_ + s0 + t;
        u[si] = mask[si] ? (loga[b] - u[si] - lse) : NEG_INF_;
    }
}

template <int FIN>
__global__ __launch_bounds__(256) void col_update2(float* __restrict__ KT,
                                                   const float* __restrict__ u,
                                                   float* __restrict__ v) {
    __shared__ float red[8];
    int b = blockIdx.y, o = blockIdx.x;
    int t = threadIdx.x;
    float* kt = KT + ((size_t)b * O_ + o) * S_;
    const float* ub = u + (size_t)b * S_;
    float vold = v[b * O_ + o];
    float xs[16];
    float m = -INFINITY, a = 0.f;
#pragma unroll
    for (int k = 0; k < 4; ++k) {
        int s = k * 1024 + t * 4;
        float4 kx = *(const float4*)(kt + s);
        float4 ux = *(const float4*)(ub + s);
        float x0 = kx.x + ux.x, x1 = kx.y + ux.y, x2 = kx.z + ux.z, x3 = kx.w + ux.w;
        if (FIN) { xs[k*4] = x0; xs[k*4+1] = x1; xs[k*4+2] = x2; xs[k*4+3] = x3; }
        float cm = fmaxf(fmaxf(x0, x1), fmaxf(x2, x3));
        float nm = fmaxf(m, cm);
        a = a * __expf(m - nm) + __expf(x0 - nm) + __expf(x1 - nm)
                               + __expf(x2 - nm) + __expf(x3 - nm);
        m = nm;
    }
#pragma unroll
    for (int off = 1; off < 64; off <<= 1) {
        float mo = __shfl_xor(m, off), ao = __shfl_xor(a, off);
        float nm = fmaxf(m, mo);
        a = a * __expf(m - nm) + ao * __expf(mo - nm);
        m = nm;
    }
    int w = t >> 6;
    if ((t & 63) == 0) { red[w * 2] = m; red[w * 2 + 1] = a; }
    __syncthreads();
    float M = red[0], A = red[1];
#pragma unroll
    for (int i = 1; i < 4; ++i) {
        float mi = red[i * 2], ai = red[i * 2 + 1];
        float nm = fmaxf(M, mi);
        A = A * __expf(M - nm) + ai * __expf(mi - nm);
        M = nm;
    }
    float lse = M + logf(A);
    float vn = -vold - lse;
    if (t == 0) v[b * O_ + o] = vn;
    if (FIN) {
        float oo = (float)o * (1.0f / O_);
#pragma unroll
        for (int k = 0; k < 4; ++k) {
            int s = k * 1024 + t * 4;
            float4 r;
            float rr[4];
#pragma unroll
            for (int j = 0; j < 4; ++j) {
                float d = (float)(s + j) * (1.0f / S_) - oo;
                rr[j] = 4096.0f * __expf(xs[k * 4 + j] + vn - 100.0f * d * d);
            }
            r.x = rr[0]; r.y = rr[1]; r.z = rr[2]; r.w = rr[3];
            *(float4*)(kt + s) = r;
        }
    }
}

// ================= launch =================

extern "C" void kernel_launch(void* const* d_in, const int* in_sizes, int n_in,
                              void* d_out, int out_size, void* d_ws, size_t ws_size,
                              hipStream_t stream) {
    const float* input  = (const float*)d_in[0];
    const float* target = (const float*)d_in[1];
    const float* iou    = (const float*)d_in[2];
    const int*   mask   = (const int*)d_in[3];
    float* out = (float*)d_out;
    float* wsf = (float*)d_ws;

    const size_t N_IN = (size_t)B_ * S_ * D_;   // 8388608
    const size_t N_TG = (size_t)B_ * O_ * D_;   // 1048576
    const size_t NK   = (size_t)B_ * S_ * O_;   // 33554432

    float* u    = wsf;
    float* v    = u + (size_t)B_ * S_;
    float* loga = v + (size_t)B_ * O_;
    float* u1c  = loga + 16;
    float* Knat = u1c + (size_t)B_ * S_;
    char*  region = (char*)(Knat + NK);

    // tier-A overlay: colma then zh
    float2* colma = (float2*)region;
    _Float16* zh = (_Float16*)(colma + (size_t)B_ * 64 * O_);
    size_t need_A = (size_t)((char*)(zh + NK) - (char*)d_ws);

    // tier-B: colma only
    size_t need_B = (size_t)((char*)(colma + (size_t)B_ * 64 * O_) - (char*)d_ws);

    // fallback layout (round-3, needs splits)
    unsigned short* m_in_hi = (unsigned short*)(loga + 16);
    unsigned short* m_in_lo = m_in_hi + N_IN;
    unsigned short* m_tg_hi = m_in_lo + N_IN;
    unsigned short* m_tg_lo = m_tg_hi + N_TG;
    size_t need_mid = (size_t)((char*)(m_tg_lo + N_TG) - (char*)d_ws);

    init_kernel<<<B_, 256, 0, stream>>>(mask, u, v, loga);
    int n4A = (int)(N_IN / 4), n4B = (int)(N_TG / 4);

    if (ws_size >= need_A) {
        gemm_nat<<<dim3(S_ / 256, O_ / 64, B_), 256, 0, stream>>>(input, target, iou, Knat);
        sink_first_z<<<dim3(S_ / 64, B_), 256, 0, stream>>>(Knat, u, u1c, zh, colma, mask, loga);
        finalize_v<<<dim3(O_ / 64, B_), 256, 0, stream>>>(colma, v);
        for (int it = 1; it < MAX_ITER_; ++it) {
            sink_late<<<dim3(S_ / 64, B_), 256, 0, stream>>>(zh, v, u, u1c, colma, mask, loga);
            finalize_v<<<dim3(O_ / 64, B_), 256, 0, stream>>>(colma, v);
        }
        final_tr_z<<<dim3(S_ / 64, O_ / 64, B_), 256, 0, stream>>>(zh, u, u1c, v, out);
    } else if (ws_size >= need_B) {
        gemm_nat<<<dim3(S_ / 256, O_ / 64, B_), 256, 0, stream>>>(input, target, iou, Knat);
        for (int it = 0; it < MAX_ITER_; ++it) {
            if (it == 0)
                sink_iter<1><<<dim3(S_ / 64, B_), 256, 0, stream>>>(Knat, v, u, colma, mask, loga);
            else
                sink_iter<0><<<dim3(S_ / 64, B_), 256, 0, stream>>>(Knat, v, u, colma, mask, loga);
            finalize_v<<<dim3(O_ / 64, B_), 256, 0, stream>>>(colma, v);
        }
        final_tr<<<dim3(S_ / 64, O_ / 64, B_), 256, 0, stream>>>(Knat, u, v, out);
    } else if (ws_size >= need_mid) {
        split_kernel<<<(n4A + n4B + 255) / 256, 256, 0, stream>>>(
            input, m_in_hi, m_in_lo, n4A, target, m_tg_hi, m_tg_lo, n4B);
        gemm_kt2<<<dim3(S_ / 64, O_ / 64, B_), 256, 0, stream>>>(m_in_hi, m_in_lo, m_tg_hi, m_tg_lo, iou, out);
        for (int it = 0; it < MAX_ITER_; ++it) {
            row_update2<<<dim3(S_ / 128, B_), 256, 0, stream>>>(out, v, u, mask, loga);
            if (it < MAX_ITER_ - 1)
                col_update2<0><<<dim3(O_, B_), 256, 0, stream>>>(out, u, v);
            else
                col_update2<1><<<dim3(O_, B_), 256, 0, stream>>>(out, u, v);
        }
    }
}